// Round 15
// baseline (427.018 us; speedup 1.0000x reference)
//
#include <hip/hip_runtime.h>
#include <math.h>

#define VOXN 32768

typedef __attribute__((ext_vector_type(8))) short bf16x8;
typedef __attribute__((ext_vector_type(4))) float f32x4;

// ---- workspace layout (float offsets) ----
constexpr int OFF_STATS_Y   = 0;        // 512
constexpr int OFF_STATS_X2P = 512;      // 256
constexpr int OFF_STATS_H   = 768;      // 512
constexpr int OFF_TPAR      = 1280;     // 1024*16 packed tap params (SORTED order)
constexpr int OFF_W1A       = 17664;    // 32768: bf16 A-frags for w1
constexpr int OFF_W2A       = 83200;    // 16384: bf16 A-frags for w2 (M=128,K=256)
constexpr int OFF_W3AT      = 115968;   // 4096
constexpr int OFF_W3BT      = 120064;   // 5120
constexpr int OFF_W3CT      = 125184;   // 6144
constexpr int OFF_W3DT      = 131328;   // 7168
constexpr int OFF_W4T       = 138496;   // 2048
constexpr int OFF_YH        = 140544;   // 8388608 (y, later H)
constexpr int OFF_C0A       = OFF_YH;       // 1024 ints (dead before s1 writes y)
constexpr int OFF_PERM      = OFF_YH + 1024;// 1024 ints
constexpr int OFF_X2P       = 8529152;  // 4194304 (x2pre; ALSO hosts pvolB early)
constexpr int OFF_PVOLB     = OFF_X2P;  // 941192 uint4 (8 bf16 cube)

#define FMA4(A, W, X) { (A).x = fmaf((W).x, (X), (A).x); (A).y = fmaf((W).y, (X), (A).y); \
                        (A).z = fmaf((W).z, (X), (A).z); (A).w = fmaf((W).w, (X), (A).w); }
#define RELU4(A) { (A).x = fmaxf((A).x, 0.f); (A).y = fmaxf((A).y, 0.f); \
                   (A).z = fmaxf((A).z, 0.f); (A).w = fmaxf((A).w, 0.f); }
#define ZERO4(A) float4 A; (A).x = 0.f; (A).y = 0.f; (A).z = 0.f; (A).w = 0.f;

#define BFLY(s, q) { s += __shfl_xor(s, 32, 64); q += __shfl_xor(q, 32, 64); \
                     s += __shfl_xor(s, 16, 64); q += __shfl_xor(q, 16, 64); \
                     s += __shfl_xor(s,  8, 64); q += __shfl_xor(q,  8, 64); \
                     s += __shfl_xor(s,  4, 64); q += __shfl_xor(q,  4, 64); \
                     s += __shfl_xor(s,  2, 64); q += __shfl_xor(q,  2, 64); \
                     s += __shfl_xor(s,  1, 64); q += __shfl_xor(q,  1, 64); }
#define STASH1(V, O) { float s_ = (V), q_ = (V) * (V); BFLY(s_, q_) \
                       if (lane == (O)) { ms = s_; mq = q_; } }
#define STASH4(A, O0) STASH1((A).x, (O0)+0) STASH1((A).y, (O0)+1) \
                      STASH1((A).z, (O0)+2) STASH1((A).w, (O0)+3)

__device__ __forceinline__ unsigned short f2bf(float f) {
  unsigned int u = __float_as_uint(f);
  u += 0x7FFFu + ((u >> 16) & 1u);     // RNE
  return (unsigned short)(u >> 16);
}

__device__ __forceinline__ float corner(const float* __restrict__ im, int x, int y, int z) {
  if (x >= 33 && x < 65 && y >= 33 && y < 65 && z >= 33 && z < 65)
    return im[((z - 33) * 32 + (y - 33)) * 32 + (x - 33)];
  return 0.f;
}

__device__ __forceinline__ int tap_c0(const float* __restrict__ offset1, int k, int s) {
  float ox = fminf(fmaxf(offset1[k * 6 + s * 3 + 0] * 16.f, -1000.f), 1000.f);
  float oy = fminf(fmaxf(offset1[k * 6 + s * 3 + 1] * 16.f, -1000.f), 1000.f);
  float oz = fminf(fmaxf(offset1[k * 6 + s * 3 + 2] * 16.f, -1000.f), 1000.f);
  int sx = (int)floorf(ox), sy = (int)floorf(oy), sz = (int)floorf(oz);
  bool valid = (sx >= -33 && sx <= 32) && (sy >= -33 && sy <= 32) && (sz >= -33 && sz <= 32);
  if (!valid) { sx = sy = sz = 0; }
  return (sz + 33) * 9604 + (sy + 33) * 98 + (sx + 33);
}

// ---------------- S0a: bf16 cube volume (predicated fast fill) + keys + transposes ------
__global__ void s0a_setup(const float* __restrict__ images, const float* __restrict__ offset1,
                          const float* __restrict__ w3a, const float* __restrict__ w3b,
                          const float* __restrict__ w3c, const float* __restrict__ w3d,
                          const float* __restrict__ w4, float* __restrict__ ws)
{
  const int idx = blockIdx.x * blockDim.x + threadIdx.x;
  const int stride = gridDim.x * blockDim.x;
  for (int i = idx; i < 1280; i += stride) ws[i] = 0.f;
  uint4* qq = (uint4*)(ws + OFF_PVOLB);
  for (int i = idx; i < 941192; i += stride) {
    int x = i % 98, t = i / 98, y = t % 98, z = t / 98;
    uint4 f; f.x = 0u; f.y = 0u; f.z = 0u; f.w = 0u;
    if (x >= 32 && x <= 64 && y >= 32 && y <= 64 && z >= 32 && z <= 64) {
      float c000 = corner(images, x, y, z),     c100 = corner(images, x+1, y, z);
      float c010 = corner(images, x, y+1, z),   c110 = corner(images, x+1, y+1, z);
      float c001 = corner(images, x, y, z+1),   c101 = corner(images, x+1, y, z+1);
      float c011 = corner(images, x, y+1, z+1), c111 = corner(images, x+1, y+1, z+1);
      f.x = (unsigned int)f2bf(c000) | ((unsigned int)f2bf(c100) << 16);
      f.y = (unsigned int)f2bf(c010) | ((unsigned int)f2bf(c110) << 16);
      f.z = (unsigned int)f2bf(c001) | ((unsigned int)f2bf(c101) << 16);
      f.w = (unsigned int)f2bf(c011) | ((unsigned int)f2bf(c111) << 16);
    }
    qq[i] = f;
  }
  int* c0a = (int*)(ws + OFF_C0A);
  for (int k = idx; k < 1024; k += stride) c0a[k] = tap_c0(offset1, k, 0);
  for (int i = idx; i < 4096;  i += stride) { int o = i & 31,  c = i >> 5; ws[OFF_W3AT + i] = w3a[o * 128 + c]; }
  for (int i = idx; i < 5120;  i += stride) { int o = i & 31,  c = i >> 5; ws[OFF_W3BT + i] = w3b[o * 160 + c]; }
  for (int i = idx; i < 6144;  i += stride) { int o = i & 31,  c = i >> 5; ws[OFF_W3CT + i] = w3c[o * 192 + c]; }
  for (int i = idx; i < 7168;  i += stride) { int o = i & 31,  c = i >> 5; ws[OFF_W3DT + i] = w3d[o * 224 + c]; }
  for (int i = idx; i < 2048;  i += stride) { int l = i & 7,   c = i >> 3; ws[OFF_W4T + i] = w4[l * 256 + c]; }
}

// ---------------- S0b: rank-sort taps by c0 within each group ----------------
__global__ void s0b_rank(float* __restrict__ ws)
{
  const int idx = blockIdx.x * blockDim.x + threadIdx.x;
  if (idx >= 1024) return;
  const int g = idx >> 8, k = idx & 255;
  const int* c0a = (const int*)(ws + OFF_C0A);
  int* perm = (int*)(ws + OFF_PERM);
  const int my = c0a[g * 256 + k];
  int rank = 0;
  for (int j = 0; j < 256; ++j) {
    int cj = c0a[g * 256 + j];
    rank += (cj < my) || (cj == my && j < k);
  }
  perm[g * 256 + rank] = k;
}

// ---------------- S0c: permuted tap params + bf16 A-frag packs (w1, w2) ----------------
__global__ void s0c_build(const float* __restrict__ offset1, const float* __restrict__ w1,
                          const float* __restrict__ w2, float* __restrict__ ws)
{
  const int idx = blockIdx.x * blockDim.x + threadIdx.x;
  const int stride = gridDim.x * blockDim.x;
  const int* perm = (const int*)(ws + OFF_PERM);
  for (int p = idx; p < 1024; p += stride) {
    const int g = p >> 8;
    const int k = g * 256 + perm[p];
    float* tp = ws + OFF_TPAR + p * 16;
    for (int s = 0; s < 2; ++s) {
      float ox = fminf(fmaxf(offset1[k * 6 + s * 3 + 0] * 16.f, -1000.f), 1000.f);
      float oy = fminf(fmaxf(offset1[k * 6 + s * 3 + 1] * 16.f, -1000.f), 1000.f);
      float oz = fminf(fmaxf(offset1[k * 6 + s * 3 + 2] * 16.f, -1000.f), 1000.f);
      float fxf = floorf(ox), fyf = floorf(oy), fzf = floorf(oz);
      float fx = ox - fxf, fy = oy - fyf, fz = oz - fzf;
      int sx = (int)fxf, sy = (int)fyf, sz = (int)fzf;
      bool valid = (sx >= -33 && sx <= 32) && (sy >= -33 && sy <= 32) && (sz >= -33 && sz <= 32);
      if (!valid) { sx = sy = sz = 0; }
      float vm = valid ? 1.f : 0.f;
      int c0 = (sz + 33) * 9604 + (sy + 33) * 98 + (sx + 33);
      float sgn = s ? -1.f : 1.f;
      float wy0 = 1.f - fy, wy1 = fy, wz0 = 1.f - fz, wz1 = fz;
      tp[s * 8 + 0] = __int_as_float(c0);
      tp[s * 8 + 1] = vm * (1.f - fx);
      tp[s * 8 + 2] = vm * fx;
      tp[s * 8 + 3] = vm * sgn * wz0 * wy0;
      tp[s * 8 + 4] = vm * sgn * wz0 * wy1;
      tp[s * 8 + 5] = vm * sgn * wz1 * wy0;
      tp[s * 8 + 6] = vm * sgn * wz1 * wy1;
      tp[s * 8 + 7] = 0.f;
    }
  }
  for (int i = idx; i < 32768; i += stride) {
    int jp = i & 3;
    int l  = (i >> 2) & 63;
    int ks = (i >> 8) & 7;
    int mt = (i >> 11) & 3;
    int g  = i >> 13;
    int row = mt * 16 + (l & 15);
    int kbase = g * 256 + ks * 32 + (l >> 4) * 8 + jp * 2;
    int ka = perm[kbase], kb = perm[kbase + 1];
    unsigned short b0 = f2bf(w1[g * 16384 + row * 256 + ka]);
    unsigned short b1 = f2bf(w1[g * 16384 + row * 256 + kb]);
    ws[OFF_W1A + i] = __uint_as_float((unsigned int)b0 | ((unsigned int)b1 << 16));
  }
  for (int i = idx; i < 16384; i += stride) {
    int jp = i & 3;
    int l  = (i >> 2) & 63;
    int ks = (i >> 8) & 7;
    int mt = i >> 11;              // 0..7
    int row = mt * 16 + (l & 15);
    int k = ks * 32 + (l >> 4) * 8 + jp * 2;
    unsigned short b0 = f2bf(w2[row * 256 + k]);
    unsigned short b1 = f2bf(w2[row * 256 + k + 1]);
    ws[OFF_W2A + i] = __uint_as_float((unsigned int)b0 | ((unsigned int)b1 << 16));
  }
}

// one tap from the bf16-cube volume: ONE uint4 load
__device__ __forceinline__ float tapB(const uint4* __restrict__ Q, int vbase,
                                      const float4 t0, const float4 t1)
{
  uint4 c = Q[vbase + __float_as_int(t0.x)];
  float c0 = __uint_as_float(c.x << 16), c1 = __uint_as_float(c.x & 0xffff0000u);
  float c2 = __uint_as_float(c.y << 16), c3 = __uint_as_float(c.y & 0xffff0000u);
  float c4 = __uint_as_float(c.z << 16), c5 = __uint_as_float(c.z & 0xffff0000u);
  float c6 = __uint_as_float(c.w << 16), c7 = __uint_as_float(c.w & 0xffff0000u);
  float h0 = c0 * t0.y + c1 * t0.z;
  float h1 = c2 * t0.y + c3 * t0.z;
  float h2 = c4 * t0.y + c5 * t0.z;
  float h3 = c6 * t0.y + c7 * t0.z;
  return h0 * t0.w + h1 * t1.x + h2 * t1.y + h3 * t1.z;
}

// ---------------- S1: fused gather + MFMA, 64-voxel blocks, 8 blocks/CU ----------------
// 256 thr = 4 waves; wave wv gathers k-quarter [wv*16,+16) of each 64-k chunk for its
// 64 voxels. MFMA: wave wv = m-tile (16 rows of this group's 64), nt 0..3.
__global__ __launch_bounds__(256, 8) void s1_gather_gemm(
    const uint4* __restrict__ pvolB, const float* __restrict__ tparP,
    const float4* __restrict__ apack, float* __restrict__ y, float* __restrict__ stats_y)
{
  __shared__ unsigned short xt[64 * 72];   // 9216 B
  const int tid = threadIdx.x;
  const int lane = tid & 63;
  const int wv = tid >> 6;
  const int g = blockIdx.y;
  const int v0 = blockIdx.x * 64;
  const int v = v0 + lane;
  const int vbase = (v >> 10) * 9604 + ((v >> 5) & 31) * 98 + (v & 31);
  const float4* tq_base = (const float4*)(tparP + g * 4096);

  f32x4 acc[4];
  #pragma unroll
  for (int i = 0; i < 4; ++i) acc[i] = (f32x4){0.f, 0.f, 0.f, 0.f};

  for (int ch = 0; ch < 4; ++ch) {
    const int kb = ch * 64 + wv * 16;
    __syncthreads();
    #pragma unroll 2
    for (int i2 = 0; i2 < 16; i2 += 2) {
      const int kt = kb + i2;
      float4 t0 = tq_base[kt*4+0], t1 = tq_base[kt*4+1];
      float4 t2 = tq_base[kt*4+2], t3 = tq_base[kt*4+3];
      float xv0 = tapB(pvolB, vbase, t0, t1) + tapB(pvolB, vbase, t2, t3);
      float4 u0 = tq_base[kt*4+4], u1 = tq_base[kt*4+5];
      float4 u2 = tq_base[kt*4+6], u3 = tq_base[kt*4+7];
      float xv1 = tapB(pvolB, vbase, u0, u1) + tapB(pvolB, vbase, u2, u3);
      unsigned int pk = (unsigned int)f2bf(xv0) | ((unsigned int)f2bf(xv1) << 16);
      *(unsigned int*)&xt[lane * 72 + wv * 16 + i2] = pk;
    }
    __syncthreads();
    #pragma unroll
    for (int s = 0; s < 2; ++s) {
      float4 araw = apack[(((g * 4 + wv) * 8) + ch * 2 + s) * 64 + lane];
      bf16x8 a = *reinterpret_cast<bf16x8*>(&araw);
      #pragma unroll
      for (int nt = 0; nt < 4; ++nt) {
        const unsigned short* bp = &xt[(nt * 16 + (lane & 15)) * 72 + s * 32 + (lane >> 4) * 8];
        float4 braw = *(const float4*)bp;
        bf16x8 b = *reinterpret_cast<bf16x8*>(&braw);
        acc[nt] = __builtin_amdgcn_mfma_f32_16x16x32_bf16(a, b, acc[nt], 0, 0, 0);
      }
    }
  }
  const int obase = g << 6;
  float srow0 = 0.f, srow1 = 0.f, srow2 = 0.f, srow3 = 0.f;
  float qrow0 = 0.f, qrow1 = 0.f, qrow2 = 0.f, qrow3 = 0.f;
  #pragma unroll
  for (int nt = 0; nt < 4; ++nt) {
    const int col = v0 + nt * 16 + (lane & 15);
    const int rbase = obase + wv * 16 + (lane >> 4) * 4;
    float e0 = acc[nt][0], e1 = acc[nt][1], e2 = acc[nt][2], e3 = acc[nt][3];
    y[(size_t)(rbase + 0) * VOXN + col] = e0;
    y[(size_t)(rbase + 1) * VOXN + col] = e1;
    y[(size_t)(rbase + 2) * VOXN + col] = e2;
    y[(size_t)(rbase + 3) * VOXN + col] = e3;
    srow0 += e0; qrow0 += e0 * e0;
    srow1 += e1; qrow1 += e1 * e1;
    srow2 += e2; qrow2 += e2 * e2;
    srow3 += e3; qrow3 += e3 * e3;
  }
  #define ROWRED(S, Q, R) { \
    float s_ = S, q_ = Q; \
    s_ += __shfl_xor(s_, 1, 64); q_ += __shfl_xor(q_, 1, 64); \
    s_ += __shfl_xor(s_, 2, 64); q_ += __shfl_xor(q_, 2, 64); \
    s_ += __shfl_xor(s_, 4, 64); q_ += __shfl_xor(q_, 4, 64); \
    s_ += __shfl_xor(s_, 8, 64); q_ += __shfl_xor(q_, 8, 64); \
    if ((lane & 15) == 0) { \
      int row = obase + wv * 16 + (lane >> 4) * 4 + (R); \
      atomicAdd(&stats_y[row], s_); atomicAdd(&stats_y[256 + row], q_); } }
  ROWRED(srow0, qrow0, 0) ROWRED(srow1, qrow1, 1)
  ROWRED(srow2, qrow2, 2) ROWRED(srow3, qrow3, 3)
  #undef ROWRED
}

// ---------------- S2: x1 = relu(BN(y)) -> bf16 -> MFMA vs w2, 64-voxel blocks ----------
// 512 thr = 8 waves; 64 voxels; all 128 outputs. Wave wv stages 8 channels/chunk and
// computes m-tile wv. grid 512 -> 2 blocks/CU, 16 waves/CU.
__global__ __launch_bounds__(512) void s2_bn_gemm(
    const float* __restrict__ y, const float* __restrict__ stats_y,
    const float* __restrict__ g1, const float* __restrict__ b1,
    const float4* __restrict__ w2a, float* __restrict__ x2p, float* __restrict__ stats_x2p)
{
  __shared__ float As[256], Bs[256];
  __shared__ unsigned short xt[64 * 72];   // 9216 B
  const int tid = threadIdx.x;
  const int lane = tid & 63;
  const int wv = tid >> 6;          // 0..7: stage-channel-group & m-tile
  const int n = tid & 63;
  const int v0 = blockIdx.x * 64;
  const int v = v0 + n;
  if (tid < 256) {
    float m = stats_y[tid] * (1.f / VOXN);
    float vv = stats_y[256 + tid] * (1.f / VOXN) - m * m;
    float a = g1[tid] * rsqrtf(vv + 1e-5f);
    As[tid] = a; Bs[tid] = b1[tid] - m * a;
  }
  f32x4 acc[4];
  #pragma unroll
  for (int i = 0; i < 4; ++i) acc[i] = (f32x4){0.f, 0.f, 0.f, 0.f};

  for (int ch = 0; ch < 4; ++ch) {
    const int kb = ch * 64 + wv * 8;
    __syncthreads();
    #pragma unroll
    for (int i2 = 0; i2 < 8; i2 += 2) {
      const int c = kb + i2;
      float t0 = fmaxf(fmaf(y[(size_t)c * VOXN + v], As[c], Bs[c]), 0.f);
      float t1 = fmaxf(fmaf(y[(size_t)(c + 1) * VOXN + v], As[c + 1], Bs[c + 1]), 0.f);
      unsigned int pk = (unsigned int)f2bf(t0) | ((unsigned int)f2bf(t1) << 16);
      *(unsigned int*)&xt[n * 72 + wv * 8 + i2] = pk;
    }
    __syncthreads();
    #pragma unroll
    for (int s = 0; s < 2; ++s) {
      float4 araw = w2a[((wv * 8) + ch * 2 + s) * 64 + lane];
      bf16x8 a = *reinterpret_cast<bf16x8*>(&araw);
      #pragma unroll
      for (int nt = 0; nt < 4; ++nt) {
        const unsigned short* bp = &xt[(nt * 16 + (lane & 15)) * 72 + s * 32 + (lane >> 4) * 8];
        float4 braw = *(const float4*)bp;
        bf16x8 b = *reinterpret_cast<bf16x8*>(&braw);
        acc[nt] = __builtin_amdgcn_mfma_f32_16x16x32_bf16(a, b, acc[nt], 0, 0, 0);
      }
    }
  }
  float srow0 = 0.f, srow1 = 0.f, srow2 = 0.f, srow3 = 0.f;
  float qrow0 = 0.f, qrow1 = 0.f, qrow2 = 0.f, qrow3 = 0.f;
  #pragma unroll
  for (int nt = 0; nt < 4; ++nt) {
    const int col = v0 + nt * 16 + (lane & 15);
    const int rbase = wv * 16 + (lane >> 4) * 4;
    float e0 = acc[nt][0], e1 = acc[nt][1], e2 = acc[nt][2], e3 = acc[nt][3];
    x2p[(size_t)(rbase + 0) * VOXN + col] = e0;
    x2p[(size_t)(rbase + 1) * VOXN + col] = e1;
    x2p[(size_t)(rbase + 2) * VOXN + col] = e2;
    x2p[(size_t)(rbase + 3) * VOXN + col] = e3;
    srow0 += e0; qrow0 += e0 * e0;
    srow1 += e1; qrow1 += e1 * e1;
    srow2 += e2; qrow2 += e2 * e2;
    srow3 += e3; qrow3 += e3 * e3;
  }
  #define ROWRED2(S, Q, R) { \
    float s_ = S, q_ = Q; \
    s_ += __shfl_xor(s_, 1, 64); q_ += __shfl_xor(q_, 1, 64); \
    s_ += __shfl_xor(s_, 2, 64); q_ += __shfl_xor(q_, 2, 64); \
    s_ += __shfl_xor(s_, 4, 64); q_ += __shfl_xor(q_, 4, 64); \
    s_ += __shfl_xor(s_, 8, 64); q_ += __shfl_xor(q_, 8, 64); \
    if ((lane & 15) == 0) { \
      int row = wv * 16 + (lane >> 4) * 4 + (R); \
      atomicAdd(&stats_x2p[row], s_); atomicAdd(&stats_x2p[128 + row], q_); } }
  ROWRED2(srow0, qrow0, 0) ROWRED2(srow1, qrow1, 1)
  ROWRED2(srow2, qrow2, 2) ROWRED2(srow3, qrow3, 3)
  #undef ROWRED2
}

// ---------------- S3: x2 = BN(x2pre) -> H[0:128]; ha -> H[128+qh*4 ..] (8-way split) ----
__global__ __launch_bounds__(256) void s3_x2_ha(
    const float* __restrict__ x2p, const float* __restrict__ stats_x2p,
    const float* __restrict__ g2, const float* __restrict__ b2,
    const float* __restrict__ w3at, float* __restrict__ H, float* __restrict__ stats_H)
{
  __shared__ float As[128], Bs[128];
  __shared__ float redS[4][4], redQ[4][4];
  const int tid = threadIdx.x;
  const int lane = tid & 63;
  const int wv = tid >> 6;
  if (tid < 128) {
    float m = stats_x2p[tid] * (1.f / VOXN);
    float vv = stats_x2p[128 + tid] * (1.f / VOXN) - m * m;
    float a = g2[tid] * rsqrtf(vv + 1e-5f);
    As[tid] = a; Bs[tid] = b2[tid] - m * a;
    if (blockIdx.x == 0 && blockIdx.y == 0) {
      float mean = b2[tid];
      float var = a * a * vv;
      stats_H[tid] = mean * (float)VOXN;
      stats_H[256 + tid] = (var + mean * mean) * (float)VOXN;
    }
  }
  __syncthreads();
  const int qh = blockIdx.y;           // 0..7 -> 4 outputs
  const int n = blockIdx.x * 256 + tid;
  ZERO4(a0)
  #pragma unroll 8
  for (int c = 0; c < 128; ++c) {
    float x2v = fmaf(x2p[(size_t)c * VOXN + n], As[c], Bs[c]);
    if (qh == 0) H[(size_t)c * VOXN + n] = x2v;
    const float4* wk = (const float4*)(w3at + c * 32 + qh * 4);
    float4 w = wk[0];
    FMA4(a0, w, x2v)
  }
  RELU4(a0)
  const int ob = 128 + qh * 4;
  H[((size_t)(ob + 0)) * VOXN + n] = a0.x;
  H[((size_t)(ob + 1)) * VOXN + n] = a0.y;
  H[((size_t)(ob + 2)) * VOXN + n] = a0.z;
  H[((size_t)(ob + 3)) * VOXN + n] = a0.w;
  float ms = 0.f, mq = 0.f;
  STASH4(a0, 0)
  if (lane < 4) { redS[wv][lane] = ms; redQ[wv][lane] = mq; }
  __syncthreads();
  if (tid < 4) {
    float s = redS[0][tid] + redS[1][tid] + redS[2][tid] + redS[3][tid];
    float qq = redQ[0][tid] + redQ[1][tid] + redQ[2][tid] + redQ[3][tid];
    atomicAdd(&stats_H[ob + tid], s);
    atomicAdd(&stats_H[256 + ob + tid], qq);
  }
}

// ---------------- S4/5/6: h = relu(w @ BN(H[0:CIN])) -> H[och + qh*4 ..] (8-way) ----------
template<int CIN>
__global__ __launch_bounds__(256) void s_dense(
    const float* __restrict__ Hin, const float* __restrict__ stats_H,
    const float* __restrict__ g, const float* __restrict__ b,
    const float* __restrict__ wt, float* __restrict__ H, float* __restrict__ stats_out, int och)
{
  __shared__ float As[CIN], Bs[CIN];
  __shared__ float redS[4][4], redQ[4][4];
  const int tid = threadIdx.x;
  const int lane = tid & 63;
  const int wv = tid >> 6;
  if (tid < CIN) {
    float m = stats_H[tid] * (1.f / VOXN);
    float vv = stats_H[256 + tid] * (1.f / VOXN) - m * m;
    float a = g[tid] * rsqrtf(vv + 1e-5f);
    As[tid] = a; Bs[tid] = b[tid] - m * a;
  }
  __syncthreads();
  const int osub = blockIdx.y * 4;     // 0..7 -> 4 outputs
  const int n = blockIdx.x * 256 + tid;
  ZERO4(a0)
  #pragma unroll 8
  for (int c = 0; c < CIN; ++c) {
    float t = fmaf(Hin[(size_t)c * VOXN + n], As[c], Bs[c]);
    const float4* wk = (const float4*)(wt + c * 32 + osub);
    float4 w = wk[0];
    FMA4(a0, w, t)
  }
  RELU4(a0)
  const int ob = och + osub;
  H[((size_t)(ob + 0)) * VOXN + n] = a0.x;
  H[((size_t)(ob + 1)) * VOXN + n] = a0.y;
  H[((size_t)(ob + 2)) * VOXN + n] = a0.z;
  H[((size_t)(ob + 3)) * VOXN + n] = a0.w;
  float ms = 0.f, mq = 0.f;
  STASH4(a0, 0)
  if (lane < 4) { redS[wv][lane] = ms; redQ[wv][lane] = mq; }
  __syncthreads();
  if (tid < 4) {
    float s = redS[0][tid] + redS[1][tid] + redS[2][tid] + redS[3][tid];
    float qq = redQ[0][tid] + redQ[1][tid] + redQ[2][tid] + redQ[3][tid];
    atomicAdd(&stats_out[ob + tid], s);
    atomicAdd(&stats_out[256 + ob + tid], qq);
  }
}

// ---------------- S7: 256 thr = 64 vox x 4 c-quarters; LDS combine; grid 512 ------------
__global__ __launch_bounds__(256) void s7_final(
    const float* __restrict__ H, const float* __restrict__ stats_H,
    const float* __restrict__ g3d, const float* __restrict__ b3d,
    const float* __restrict__ w4t, const float* __restrict__ b4, float* __restrict__ out)
{
  __shared__ float As[256], Bs[256];
  __shared__ float part[3][64][8];
  const int tid = threadIdx.x;
  const int vox = tid & 63;
  const int cq = tid >> 6;              // c-quarter 0..3
  const int n = blockIdx.x * 64 + vox;
  {
    float m = stats_H[tid] * (1.f / VOXN);
    float vv = stats_H[256 + tid] * (1.f / VOXN) - m * m;
    float a = g3d[tid] * rsqrtf(vv + 1e-5f);
    As[tid] = a; Bs[tid] = b3d[tid] - m * a;
  }
  __syncthreads();
  ZERO4(a0) ZERO4(a1)
  const int c0 = cq * 64;
  #pragma unroll 8
  for (int c = c0; c < c0 + 64; ++c) {
    float t = fmaf(H[(size_t)c * VOXN + n], As[c], Bs[c]);
    const float4* wk = (const float4*)(w4t + c * 8);
    float4 w;
    w = wk[0]; FMA4(a0, w, t)
    w = wk[1]; FMA4(a1, w, t)
  }
  if (cq > 0) {
    part[cq - 1][vox][0] = a0.x; part[cq - 1][vox][1] = a0.y;
    part[cq - 1][vox][2] = a0.z; part[cq - 1][vox][3] = a0.w;
    part[cq - 1][vox][4] = a1.x; part[cq - 1][vox][5] = a1.y;
    part[cq - 1][vox][6] = a1.z; part[cq - 1][vox][7] = a1.w;
  }
  __syncthreads();
  if (cq == 0) {
    float r0 = a0.x + part[0][vox][0] + part[1][vox][0] + part[2][vox][0];
    float r1 = a0.y + part[0][vox][1] + part[1][vox][1] + part[2][vox][1];
    float r2 = a0.z + part[0][vox][2] + part[1][vox][2] + part[2][vox][2];
    float r3 = a0.w + part[0][vox][3] + part[1][vox][3] + part[2][vox][3];
    float r4 = a1.x + part[0][vox][4] + part[1][vox][4] + part[2][vox][4];
    float r5 = a1.y + part[0][vox][5] + part[1][vox][5] + part[2][vox][5];
    float r6 = a1.z + part[0][vox][6] + part[1][vox][6] + part[2][vox][6];
    float r7 = a1.w + part[0][vox][7] + part[1][vox][7] + part[2][vox][7];
    out[(size_t)0 * VOXN + n] = 1.f / (1.f + expf(-(r0 + b4[0])));
    out[(size_t)1 * VOXN + n] = 1.f / (1.f + expf(-(r1 + b4[1])));
    out[(size_t)2 * VOXN + n] = 1.f / (1.f + expf(-(r2 + b4[2])));
    out[(size_t)3 * VOXN + n] = 1.f / (1.f + expf(-(r3 + b4[3])));
    out[(size_t)4 * VOXN + n] = 1.f / (1.f + expf(-(r4 + b4[4])));
    out[(size_t)5 * VOXN + n] = 1.f / (1.f + expf(-(r5 + b4[5])));
    out[(size_t)6 * VOXN + n] = 1.f / (1.f + expf(-(r6 + b4[6])));
    out[(size_t)7 * VOXN + n] = 1.f / (1.f + expf(-(r7 + b4[7])));
  }
}

extern "C" void kernel_launch(void* const* d_in, const int* in_sizes, int n_in,
                              void* d_out, int out_size, void* d_ws, size_t ws_size,
                              hipStream_t stream)
{
  const float* images  = (const float*)d_in[0];
  const float* offset1 = (const float*)d_in[1];
  const float* w1  = (const float*)d_in[2];
  const float* g1  = (const float*)d_in[3];
  const float* b1  = (const float*)d_in[4];
  const float* w2  = (const float*)d_in[5];
  const float* g2  = (const float*)d_in[6];
  const float* b2  = (const float*)d_in[7];
  const float* w3a = (const float*)d_in[8];
  const float* w3b = (const float*)d_in[9];
  const float* w3c = (const float*)d_in[10];
  const float* w3d = (const float*)d_in[11];
  const float* g3a = (const float*)d_in[12];
  const float* b3a = (const float*)d_in[13];
  const float* g3b = (const float*)d_in[14];
  const float* b3b = (const float*)d_in[15];
  const float* g3c = (const float*)d_in[16];
  const float* b3c = (const float*)d_in[17];
  const float* g3d = (const float*)d_in[18];
  const float* b3d = (const float*)d_in[19];
  const float* w4  = (const float*)d_in[20];
  const float* b4  = (const float*)d_in[21];

  float* ws  = (float*)d_ws;
  float* out = (float*)d_out;

  float* statsY = ws + OFF_STATS_Y;
  float* statsX = ws + OFF_STATS_X2P;
  float* statsH = ws + OFF_STATS_H;
  float* YH     = ws + OFF_YH;   // y, later H
  float* x2p    = ws + OFF_X2P;

  s0a_setup<<<dim3(256), dim3(256), 0, stream>>>(images, offset1, w3a, w3b, w3c, w3d, w4, ws);
  s0b_rank<<<dim3(4), dim3(256), 0, stream>>>(ws);
  s0c_build<<<dim3(64), dim3(256), 0, stream>>>(offset1, w1, w2, ws);
  s1_gather_gemm<<<dim3(512, 4), dim3(256), 0, stream>>>(
      (const uint4*)(ws + OFF_PVOLB), ws + OFF_TPAR,
      (const float4*)(ws + OFF_W1A), YH, statsY);
  s2_bn_gemm<<<dim3(512), dim3(512), 0, stream>>>(
      YH, statsY, g1, b1, (const float4*)(ws + OFF_W2A), x2p, statsX);
  s3_x2_ha<<<dim3(128, 8), dim3(256), 0, stream>>>(x2p, statsX, g2, b2, ws + OFF_W3AT, YH, statsH);
  s_dense<160><<<dim3(128, 8), dim3(256), 0, stream>>>(YH, statsH, g3a, b3a, ws + OFF_W3BT, YH, statsH, 160);
  s_dense<192><<<dim3(128, 8), dim3(256), 0, stream>>>(YH, statsH, g3b, b3b, ws + OFF_W3CT, YH, statsH, 192);
  s_dense<224><<<dim3(128, 8), dim3(256), 0, stream>>>(YH, statsH, g3c, b3c, ws + OFF_W3DT, YH, statsH, 224);
  s7_final<<<dim3(512), dim3(256), 0, stream>>>(YH, statsH, g3d, b3d, ws + OFF_W4T, b4, out);
}

// Round 16
// 384.702 us; speedup vs baseline: 1.1100x; 1.1100x over previous
//
#include <hip/hip_runtime.h>
#include <math.h>

#define VOXN 32768

typedef __attribute__((ext_vector_type(8))) short bf16x8;
typedef __attribute__((ext_vector_type(4))) float f32x4;

// ---- workspace layout (float offsets) ----
constexpr int OFF_STATS_Y   = 0;        // 512
constexpr int OFF_STATS_X2P = 512;      // 256
constexpr int OFF_STATS_H   = 768;      // 512
constexpr int OFF_TPAR      = 1280;     // 1024*16 packed tap params (SORTED order)
constexpr int OFF_W1A       = 17664;    // 32768: bf16 A-frags for w1
constexpr int OFF_W2A       = 83200;    // 16384: bf16 A-frags for w2 (M=128,K=256)
constexpr int OFF_W3AT      = 115968;   // 4096
constexpr int OFF_W3BT      = 120064;   // 5120
constexpr int OFF_W3CT      = 125184;   // 6144
constexpr int OFF_W3DT      = 131328;   // 7168
constexpr int OFF_W4T       = 138496;   // 2048
constexpr int OFF_YH        = 140544;   // 8388608 (y, later H)
constexpr int OFF_C0A       = OFF_YH;       // 1024 ints (dead before s1 writes y)
constexpr int OFF_PERM      = OFF_YH + 1024;// 1024 ints
constexpr int OFF_X2P       = 8529152;  // 4194304 (x2pre; ALSO hosts pvolB early)
constexpr int OFF_PVOLB     = OFF_X2P;  // 941192 uint4 (8 bf16 cube)

#define FMA4(A, W, X) { (A).x = fmaf((W).x, (X), (A).x); (A).y = fmaf((W).y, (X), (A).y); \
                        (A).z = fmaf((W).z, (X), (A).z); (A).w = fmaf((W).w, (X), (A).w); }
#define RELU4(A) { (A).x = fmaxf((A).x, 0.f); (A).y = fmaxf((A).y, 0.f); \
                   (A).z = fmaxf((A).z, 0.f); (A).w = fmaxf((A).w, 0.f); }
#define ZERO4(A) float4 A; (A).x = 0.f; (A).y = 0.f; (A).z = 0.f; (A).w = 0.f;

#define BFLY(s, q) { s += __shfl_xor(s, 32, 64); q += __shfl_xor(q, 32, 64); \
                     s += __shfl_xor(s, 16, 64); q += __shfl_xor(q, 16, 64); \
                     s += __shfl_xor(s,  8, 64); q += __shfl_xor(q,  8, 64); \
                     s += __shfl_xor(s,  4, 64); q += __shfl_xor(q,  4, 64); \
                     s += __shfl_xor(s,  2, 64); q += __shfl_xor(q,  2, 64); \
                     s += __shfl_xor(s,  1, 64); q += __shfl_xor(q,  1, 64); }
#define STASH1(V, O) { float s_ = (V), q_ = (V) * (V); BFLY(s_, q_) \
                       if (lane == (O)) { ms = s_; mq = q_; } }
#define STASH4(A, O0) STASH1((A).x, (O0)+0) STASH1((A).y, (O0)+1) \
                      STASH1((A).z, (O0)+2) STASH1((A).w, (O0)+3)

__device__ __forceinline__ unsigned short f2bf(float f) {
  unsigned int u = __float_as_uint(f);
  u += 0x7FFFu + ((u >> 16) & 1u);     // RNE
  return (unsigned short)(u >> 16);
}

__device__ __forceinline__ float corner(const float* __restrict__ im, int x, int y, int z) {
  if (x >= 33 && x < 65 && y >= 33 && y < 65 && z >= 33 && z < 65)
    return im[((z - 33) * 32 + (y - 33)) * 32 + (x - 33)];
  return 0.f;
}

__device__ __forceinline__ int tap_c0(const float* __restrict__ offset1, int k, int s) {
  float ox = fminf(fmaxf(offset1[k * 6 + s * 3 + 0] * 16.f, -1000.f), 1000.f);
  float oy = fminf(fmaxf(offset1[k * 6 + s * 3 + 1] * 16.f, -1000.f), 1000.f);
  float oz = fminf(fmaxf(offset1[k * 6 + s * 3 + 2] * 16.f, -1000.f), 1000.f);
  int sx = (int)floorf(ox), sy = (int)floorf(oy), sz = (int)floorf(oz);
  bool valid = (sx >= -33 && sx <= 32) && (sy >= -33 && sy <= 32) && (sz >= -33 && sz <= 32);
  if (!valid) { sx = sy = sz = 0; }
  return (sz + 33) * 9604 + (sy + 33) * 98 + (sx + 33);
}

// ---------------- S0a: bf16 cube volume (predicated fast fill) + keys + transposes ------
__global__ void s0a_setup(const float* __restrict__ images, const float* __restrict__ offset1,
                          const float* __restrict__ w3a, const float* __restrict__ w3b,
                          const float* __restrict__ w3c, const float* __restrict__ w3d,
                          const float* __restrict__ w4, float* __restrict__ ws)
{
  const int idx = blockIdx.x * blockDim.x + threadIdx.x;
  const int stride = gridDim.x * blockDim.x;
  for (int i = idx; i < 1280; i += stride) ws[i] = 0.f;
  uint4* qq = (uint4*)(ws + OFF_PVOLB);
  for (int i = idx; i < 941192; i += stride) {
    int x = i % 98, t = i / 98, y = t % 98, z = t / 98;
    uint4 f; f.x = 0u; f.y = 0u; f.z = 0u; f.w = 0u;
    if (x >= 32 && x <= 64 && y >= 32 && y <= 64 && z >= 32 && z <= 64) {
      float c000 = corner(images, x, y, z),     c100 = corner(images, x+1, y, z);
      float c010 = corner(images, x, y+1, z),   c110 = corner(images, x+1, y+1, z);
      float c001 = corner(images, x, y, z+1),   c101 = corner(images, x+1, y, z+1);
      float c011 = corner(images, x, y+1, z+1), c111 = corner(images, x+1, y+1, z+1);
      f.x = (unsigned int)f2bf(c000) | ((unsigned int)f2bf(c100) << 16);
      f.y = (unsigned int)f2bf(c010) | ((unsigned int)f2bf(c110) << 16);
      f.z = (unsigned int)f2bf(c001) | ((unsigned int)f2bf(c101) << 16);
      f.w = (unsigned int)f2bf(c011) | ((unsigned int)f2bf(c111) << 16);
    }
    qq[i] = f;
  }
  int* c0a = (int*)(ws + OFF_C0A);
  for (int k = idx; k < 1024; k += stride) c0a[k] = tap_c0(offset1, k, 0);
  for (int i = idx; i < 4096;  i += stride) { int o = i & 31,  c = i >> 5; ws[OFF_W3AT + i] = w3a[o * 128 + c]; }
  for (int i = idx; i < 5120;  i += stride) { int o = i & 31,  c = i >> 5; ws[OFF_W3BT + i] = w3b[o * 160 + c]; }
  for (int i = idx; i < 6144;  i += stride) { int o = i & 31,  c = i >> 5; ws[OFF_W3CT + i] = w3c[o * 192 + c]; }
  for (int i = idx; i < 7168;  i += stride) { int o = i & 31,  c = i >> 5; ws[OFF_W3DT + i] = w3d[o * 224 + c]; }
  for (int i = idx; i < 2048;  i += stride) { int l = i & 7,   c = i >> 3; ws[OFF_W4T + i] = w4[l * 256 + c]; }
}

// ---------------- S0b: rank-sort taps by c0 within each group ----------------
__global__ void s0b_rank(float* __restrict__ ws)
{
  const int idx = blockIdx.x * blockDim.x + threadIdx.x;
  if (idx >= 1024) return;
  const int g = idx >> 8, k = idx & 255;
  const int* c0a = (const int*)(ws + OFF_C0A);
  int* perm = (int*)(ws + OFF_PERM);
  const int my = c0a[g * 256 + k];
  int rank = 0;
  for (int j = 0; j < 256; ++j) {
    int cj = c0a[g * 256 + j];
    rank += (cj < my) || (cj == my && j < k);
  }
  perm[g * 256 + rank] = k;
}

// ---------------- S0c: permuted tap params + bf16 A-frag packs (w1, w2) ----------------
__global__ void s0c_build(const float* __restrict__ offset1, const float* __restrict__ w1,
                          const float* __restrict__ w2, float* __restrict__ ws)
{
  const int idx = blockIdx.x * blockDim.x + threadIdx.x;
  const int stride = gridDim.x * blockDim.x;
  const int* perm = (const int*)(ws + OFF_PERM);
  for (int p = idx; p < 1024; p += stride) {
    const int g = p >> 8;
    const int k = g * 256 + perm[p];
    float* tp = ws + OFF_TPAR + p * 16;
    for (int s = 0; s < 2; ++s) {
      float ox = fminf(fmaxf(offset1[k * 6 + s * 3 + 0] * 16.f, -1000.f), 1000.f);
      float oy = fminf(fmaxf(offset1[k * 6 + s * 3 + 1] * 16.f, -1000.f), 1000.f);
      float oz = fminf(fmaxf(offset1[k * 6 + s * 3 + 2] * 16.f, -1000.f), 1000.f);
      float fxf = floorf(ox), fyf = floorf(oy), fzf = floorf(oz);
      float fx = ox - fxf, fy = oy - fyf, fz = oz - fzf;
      int sx = (int)fxf, sy = (int)fyf, sz = (int)fzf;
      bool valid = (sx >= -33 && sx <= 32) && (sy >= -33 && sy <= 32) && (sz >= -33 && sz <= 32);
      if (!valid) { sx = sy = sz = 0; }
      float vm = valid ? 1.f : 0.f;
      int c0 = (sz + 33) * 9604 + (sy + 33) * 98 + (sx + 33);
      float sgn = s ? -1.f : 1.f;
      float wy0 = 1.f - fy, wy1 = fy, wz0 = 1.f - fz, wz1 = fz;
      tp[s * 8 + 0] = __int_as_float(c0);
      tp[s * 8 + 1] = vm * (1.f - fx);
      tp[s * 8 + 2] = vm * fx;
      tp[s * 8 + 3] = vm * sgn * wz0 * wy0;
      tp[s * 8 + 4] = vm * sgn * wz0 * wy1;
      tp[s * 8 + 5] = vm * sgn * wz1 * wy0;
      tp[s * 8 + 6] = vm * sgn * wz1 * wy1;
      tp[s * 8 + 7] = 0.f;
    }
  }
  for (int i = idx; i < 32768; i += stride) {
    int jp = i & 3;
    int l  = (i >> 2) & 63;
    int ks = (i >> 8) & 7;
    int mt = (i >> 11) & 3;
    int g  = i >> 13;
    int row = mt * 16 + (l & 15);
    int kbase = g * 256 + ks * 32 + (l >> 4) * 8 + jp * 2;
    int ka = perm[kbase], kb = perm[kbase + 1];
    unsigned short b0 = f2bf(w1[g * 16384 + row * 256 + ka]);
    unsigned short b1 = f2bf(w1[g * 16384 + row * 256 + kb]);
    ws[OFF_W1A + i] = __uint_as_float((unsigned int)b0 | ((unsigned int)b1 << 16));
  }
  for (int i = idx; i < 16384; i += stride) {
    int jp = i & 3;
    int l  = (i >> 2) & 63;
    int ks = (i >> 8) & 7;
    int mt = i >> 11;              // 0..7
    int row = mt * 16 + (l & 15);
    int k = ks * 32 + (l >> 4) * 8 + jp * 2;
    unsigned short b0 = f2bf(w2[row * 256 + k]);
    unsigned short b1 = f2bf(w2[row * 256 + k + 1]);
    ws[OFF_W2A + i] = __uint_as_float((unsigned int)b0 | ((unsigned int)b1 << 16));
  }
}

// one tap from the bf16-cube volume: ONE uint4 load
__device__ __forceinline__ float tapB(const uint4* __restrict__ Q, int vbase,
                                      const float4 t0, const float4 t1)
{
  uint4 c = Q[vbase + __float_as_int(t0.x)];
  float c0 = __uint_as_float(c.x << 16), c1 = __uint_as_float(c.x & 0xffff0000u);
  float c2 = __uint_as_float(c.y << 16), c3 = __uint_as_float(c.y & 0xffff0000u);
  float c4 = __uint_as_float(c.z << 16), c5 = __uint_as_float(c.z & 0xffff0000u);
  float c6 = __uint_as_float(c.w << 16), c7 = __uint_as_float(c.w & 0xffff0000u);
  float h0 = c0 * t0.y + c1 * t0.z;
  float h1 = c2 * t0.y + c3 * t0.z;
  float h2 = c4 * t0.y + c5 * t0.z;
  float h3 = c6 * t0.y + c7 * t0.z;
  return h0 * t0.w + h1 * t1.x + h2 * t1.y + h3 * t1.z;
}

// ---------------- S1: fused gather + MFMA, 64-voxel blocks, NO min-waves hint ------------
// 256 thr = 4 waves; wave wv gathers k-quarter [wv*16,+16) of each 64-k chunk for its
// 64 voxels. MFMA: wave wv = m-tile, nt 0..3. grid (512,4) = 2048 blocks;
// occupancy set by HW resources (LDS 9.2KB, ~56 VGPR -> ~8 blocks/CU), not by hint.
__global__ __launch_bounds__(256) void s1_gather_gemm(
    const uint4* __restrict__ pvolB, const float* __restrict__ tparP,
    const float4* __restrict__ apack, float* __restrict__ y, float* __restrict__ stats_y)
{
  __shared__ unsigned short xt[64 * 72];   // 9216 B
  const int tid = threadIdx.x;
  const int lane = tid & 63;
  const int wv = tid >> 6;
  const int g = blockIdx.y;
  const int v0 = blockIdx.x * 64;
  const int v = v0 + lane;
  const int vbase = (v >> 10) * 9604 + ((v >> 5) & 31) * 98 + (v & 31);
  const float4* tq_base = (const float4*)(tparP + g * 4096);

  f32x4 acc[4];
  #pragma unroll
  for (int i = 0; i < 4; ++i) acc[i] = (f32x4){0.f, 0.f, 0.f, 0.f};

  for (int ch = 0; ch < 4; ++ch) {
    const int kb = ch * 64 + wv * 16;
    __syncthreads();
    #pragma unroll 2
    for (int i2 = 0; i2 < 16; i2 += 2) {
      const int kt = kb + i2;
      float4 t0 = tq_base[kt*4+0], t1 = tq_base[kt*4+1];
      float4 t2 = tq_base[kt*4+2], t3 = tq_base[kt*4+3];
      float xv0 = tapB(pvolB, vbase, t0, t1) + tapB(pvolB, vbase, t2, t3);
      float4 u0 = tq_base[kt*4+4], u1 = tq_base[kt*4+5];
      float4 u2 = tq_base[kt*4+6], u3 = tq_base[kt*4+7];
      float xv1 = tapB(pvolB, vbase, u0, u1) + tapB(pvolB, vbase, u2, u3);
      unsigned int pk = (unsigned int)f2bf(xv0) | ((unsigned int)f2bf(xv1) << 16);
      *(unsigned int*)&xt[lane * 72 + wv * 16 + i2] = pk;
    }
    __syncthreads();
    #pragma unroll
    for (int s = 0; s < 2; ++s) {
      float4 araw = apack[(((g * 4 + wv) * 8) + ch * 2 + s) * 64 + lane];
      bf16x8 a = *reinterpret_cast<bf16x8*>(&araw);
      #pragma unroll
      for (int nt = 0; nt < 4; ++nt) {
        const unsigned short* bp = &xt[(nt * 16 + (lane & 15)) * 72 + s * 32 + (lane >> 4) * 8];
        float4 braw = *(const float4*)bp;
        bf16x8 b = *reinterpret_cast<bf16x8*>(&braw);
        acc[nt] = __builtin_amdgcn_mfma_f32_16x16x32_bf16(a, b, acc[nt], 0, 0, 0);
      }
    }
  }
  const int obase = g << 6;
  float srow0 = 0.f, srow1 = 0.f, srow2 = 0.f, srow3 = 0.f;
  float qrow0 = 0.f, qrow1 = 0.f, qrow2 = 0.f, qrow3 = 0.f;
  #pragma unroll
  for (int nt = 0; nt < 4; ++nt) {
    const int col = v0 + nt * 16 + (lane & 15);
    const int rbase = obase + wv * 16 + (lane >> 4) * 4;
    float e0 = acc[nt][0], e1 = acc[nt][1], e2 = acc[nt][2], e3 = acc[nt][3];
    y[(size_t)(rbase + 0) * VOXN + col] = e0;
    y[(size_t)(rbase + 1) * VOXN + col] = e1;
    y[(size_t)(rbase + 2) * VOXN + col] = e2;
    y[(size_t)(rbase + 3) * VOXN + col] = e3;
    srow0 += e0; qrow0 += e0 * e0;
    srow1 += e1; qrow1 += e1 * e1;
    srow2 += e2; qrow2 += e2 * e2;
    srow3 += e3; qrow3 += e3 * e3;
  }
  #define ROWRED(S, Q, R) { \
    float s_ = S, q_ = Q; \
    s_ += __shfl_xor(s_, 1, 64); q_ += __shfl_xor(q_, 1, 64); \
    s_ += __shfl_xor(s_, 2, 64); q_ += __shfl_xor(q_, 2, 64); \
    s_ += __shfl_xor(s_, 4, 64); q_ += __shfl_xor(q_, 4, 64); \
    s_ += __shfl_xor(s_, 8, 64); q_ += __shfl_xor(q_, 8, 64); \
    if ((lane & 15) == 0) { \
      int row = obase + wv * 16 + (lane >> 4) * 4 + (R); \
      atomicAdd(&stats_y[row], s_); atomicAdd(&stats_y[256 + row], q_); } }
  ROWRED(srow0, qrow0, 0) ROWRED(srow1, qrow1, 1)
  ROWRED(srow2, qrow2, 2) ROWRED(srow3, qrow3, 3)
  #undef ROWRED
}

// ---------------- S2: x1 = relu(BN(y)) -> bf16 -> MFMA vs w2, 64-voxel blocks ----------
__global__ __launch_bounds__(512) void s2_bn_gemm(
    const float* __restrict__ y, const float* __restrict__ stats_y,
    const float* __restrict__ g1, const float* __restrict__ b1,
    const float4* __restrict__ w2a, float* __restrict__ x2p, float* __restrict__ stats_x2p)
{
  __shared__ float As[256], Bs[256];
  __shared__ unsigned short xt[64 * 72];   // 9216 B
  const int tid = threadIdx.x;
  const int lane = tid & 63;
  const int wv = tid >> 6;          // 0..7: stage-channel-group & m-tile
  const int n = tid & 63;
  const int v0 = blockIdx.x * 64;
  const int v = v0 + n;
  if (tid < 256) {
    float m = stats_y[tid] * (1.f / VOXN);
    float vv = stats_y[256 + tid] * (1.f / VOXN) - m * m;
    float a = g1[tid] * rsqrtf(vv + 1e-5f);
    As[tid] = a; Bs[tid] = b1[tid] - m * a;
  }
  f32x4 acc[4];
  #pragma unroll
  for (int i = 0; i < 4; ++i) acc[i] = (f32x4){0.f, 0.f, 0.f, 0.f};

  for (int ch = 0; ch < 4; ++ch) {
    const int kb = ch * 64 + wv * 8;
    __syncthreads();
    #pragma unroll
    for (int i2 = 0; i2 < 8; i2 += 2) {
      const int c = kb + i2;
      float t0 = fmaxf(fmaf(y[(size_t)c * VOXN + v], As[c], Bs[c]), 0.f);
      float t1 = fmaxf(fmaf(y[(size_t)(c + 1) * VOXN + v], As[c + 1], Bs[c + 1]), 0.f);
      unsigned int pk = (unsigned int)f2bf(t0) | ((unsigned int)f2bf(t1) << 16);
      *(unsigned int*)&xt[n * 72 + wv * 8 + i2] = pk;
    }
    __syncthreads();
    #pragma unroll
    for (int s = 0; s < 2; ++s) {
      float4 araw = w2a[((wv * 8) + ch * 2 + s) * 64 + lane];
      bf16x8 a = *reinterpret_cast<bf16x8*>(&araw);
      #pragma unroll
      for (int nt = 0; nt < 4; ++nt) {
        const unsigned short* bp = &xt[(nt * 16 + (lane & 15)) * 72 + s * 32 + (lane >> 4) * 8];
        float4 braw = *(const float4*)bp;
        bf16x8 b = *reinterpret_cast<bf16x8*>(&braw);
        acc[nt] = __builtin_amdgcn_mfma_f32_16x16x32_bf16(a, b, acc[nt], 0, 0, 0);
      }
    }
  }
  float srow0 = 0.f, srow1 = 0.f, srow2 = 0.f, srow3 = 0.f;
  float qrow0 = 0.f, qrow1 = 0.f, qrow2 = 0.f, qrow3 = 0.f;
  #pragma unroll
  for (int nt = 0; nt < 4; ++nt) {
    const int col = v0 + nt * 16 + (lane & 15);
    const int rbase = wv * 16 + (lane >> 4) * 4;
    float e0 = acc[nt][0], e1 = acc[nt][1], e2 = acc[nt][2], e3 = acc[nt][3];
    x2p[(size_t)(rbase + 0) * VOXN + col] = e0;
    x2p[(size_t)(rbase + 1) * VOXN + col] = e1;
    x2p[(size_t)(rbase + 2) * VOXN + col] = e2;
    x2p[(size_t)(rbase + 3) * VOXN + col] = e3;
    srow0 += e0; qrow0 += e0 * e0;
    srow1 += e1; qrow1 += e1 * e1;
    srow2 += e2; qrow2 += e2 * e2;
    srow3 += e3; qrow3 += e3 * e3;
  }
  #define ROWRED2(S, Q, R) { \
    float s_ = S, q_ = Q; \
    s_ += __shfl_xor(s_, 1, 64); q_ += __shfl_xor(q_, 1, 64); \
    s_ += __shfl_xor(s_, 2, 64); q_ += __shfl_xor(q_, 2, 64); \
    s_ += __shfl_xor(s_, 4, 64); q_ += __shfl_xor(q_, 4, 64); \
    s_ += __shfl_xor(s_, 8, 64); q_ += __shfl_xor(q_, 8, 64); \
    if ((lane & 15) == 0) { \
      int row = wv * 16 + (lane >> 4) * 4 + (R); \
      atomicAdd(&stats_x2p[row], s_); atomicAdd(&stats_x2p[128 + row], q_); } }
  ROWRED2(srow0, qrow0, 0) ROWRED2(srow1, qrow1, 1)
  ROWRED2(srow2, qrow2, 2) ROWRED2(srow3, qrow3, 3)
  #undef ROWRED2
}

// ---------------- S3: x2 = BN(x2pre) -> H[0:128]; ha -> H[128+qh*4 ..] (8-way split) ----
__global__ __launch_bounds__(256) void s3_x2_ha(
    const float* __restrict__ x2p, const float* __restrict__ stats_x2p,
    const float* __restrict__ g2, const float* __restrict__ b2,
    const float* __restrict__ w3at, float* __restrict__ H, float* __restrict__ stats_H)
{
  __shared__ float As[128], Bs[128];
  __shared__ float redS[4][4], redQ[4][4];
  const int tid = threadIdx.x;
  const int lane = tid & 63;
  const int wv = tid >> 6;
  if (tid < 128) {
    float m = stats_x2p[tid] * (1.f / VOXN);
    float vv = stats_x2p[128 + tid] * (1.f / VOXN) - m * m;
    float a = g2[tid] * rsqrtf(vv + 1e-5f);
    As[tid] = a; Bs[tid] = b2[tid] - m * a;
    if (blockIdx.x == 0 && blockIdx.y == 0) {
      float mean = b2[tid];
      float var = a * a * vv;
      stats_H[tid] = mean * (float)VOXN;
      stats_H[256 + tid] = (var + mean * mean) * (float)VOXN;
    }
  }
  __syncthreads();
  const int qh = blockIdx.y;           // 0..7 -> 4 outputs
  const int n = blockIdx.x * 256 + tid;
  ZERO4(a0)
  #pragma unroll 8
  for (int c = 0; c < 128; ++c) {
    float x2v = fmaf(x2p[(size_t)c * VOXN + n], As[c], Bs[c]);
    if (qh == 0) H[(size_t)c * VOXN + n] = x2v;
    const float4* wk = (const float4*)(w3at + c * 32 + qh * 4);
    float4 w = wk[0];
    FMA4(a0, w, x2v)
  }
  RELU4(a0)
  const int ob = 128 + qh * 4;
  H[((size_t)(ob + 0)) * VOXN + n] = a0.x;
  H[((size_t)(ob + 1)) * VOXN + n] = a0.y;
  H[((size_t)(ob + 2)) * VOXN + n] = a0.z;
  H[((size_t)(ob + 3)) * VOXN + n] = a0.w;
  float ms = 0.f, mq = 0.f;
  STASH4(a0, 0)
  if (lane < 4) { redS[wv][lane] = ms; redQ[wv][lane] = mq; }
  __syncthreads();
  if (tid < 4) {
    float s = redS[0][tid] + redS[1][tid] + redS[2][tid] + redS[3][tid];
    float qq = redQ[0][tid] + redQ[1][tid] + redQ[2][tid] + redQ[3][tid];
    atomicAdd(&stats_H[ob + tid], s);
    atomicAdd(&stats_H[256 + ob + tid], qq);
  }
}

// ---------------- S4/5/6: h = relu(w @ BN(H[0:CIN])) -> H[och + qh*4 ..] (8-way) ----------
template<int CIN>
__global__ __launch_bounds__(256) void s_dense(
    const float* __restrict__ Hin, const float* __restrict__ stats_H,
    const float* __restrict__ g, const float* __restrict__ b,
    const float* __restrict__ wt, float* __restrict__ H, float* __restrict__ stats_out, int och)
{
  __shared__ float As[CIN], Bs[CIN];
  __shared__ float redS[4][4], redQ[4][4];
  const int tid = threadIdx.x;
  const int lane = tid & 63;
  const int wv = tid >> 6;
  if (tid < CIN) {
    float m = stats_H[tid] * (1.f / VOXN);
    float vv = stats_H[256 + tid] * (1.f / VOXN) - m * m;
    float a = g[tid] * rsqrtf(vv + 1e-5f);
    As[tid] = a; Bs[tid] = b[tid] - m * a;
  }
  __syncthreads();
  const int osub = blockIdx.y * 4;     // 0..7 -> 4 outputs
  const int n = blockIdx.x * 256 + tid;
  ZERO4(a0)
  #pragma unroll 8
  for (int c = 0; c < CIN; ++c) {
    float t = fmaf(Hin[(size_t)c * VOXN + n], As[c], Bs[c]);
    const float4* wk = (const float4*)(wt + c * 32 + osub);
    float4 w = wk[0];
    FMA4(a0, w, t)
  }
  RELU4(a0)
  const int ob = och + osub;
  H[((size_t)(ob + 0)) * VOXN + n] = a0.x;
  H[((size_t)(ob + 1)) * VOXN + n] = a0.y;
  H[((size_t)(ob + 2)) * VOXN + n] = a0.z;
  H[((size_t)(ob + 3)) * VOXN + n] = a0.w;
  float ms = 0.f, mq = 0.f;
  STASH4(a0, 0)
  if (lane < 4) { redS[wv][lane] = ms; redQ[wv][lane] = mq; }
  __syncthreads();
  if (tid < 4) {
    float s = redS[0][tid] + redS[1][tid] + redS[2][tid] + redS[3][tid];
    float qq = redQ[0][tid] + redQ[1][tid] + redQ[2][tid] + redQ[3][tid];
    atomicAdd(&stats_out[ob + tid], s);
    atomicAdd(&stats_out[256 + ob + tid], qq);
  }
}

// ---------------- S7: 256 thr = 64 vox x 4 c-quarters; LDS combine; grid 512 ------------
__global__ __launch_bounds__(256) void s7_final(
    const float* __restrict__ H, const float* __restrict__ stats_H,
    const float* __restrict__ g3d, const float* __restrict__ b3d,
    const float* __restrict__ w4t, const float* __restrict__ b4, float* __restrict__ out)
{
  __shared__ float As[256], Bs[256];
  __shared__ float part[3][64][8];
  const int tid = threadIdx.x;
  const int vox = tid & 63;
  const int cq = tid >> 6;              // c-quarter 0..3
  const int n = blockIdx.x * 64 + vox;
  {
    float m = stats_H[tid] * (1.f / VOXN);
    float vv = stats_H[256 + tid] * (1.f / VOXN) - m * m;
    float a = g3d[tid] * rsqrtf(vv + 1e-5f);
    As[tid] = a; Bs[tid] = b3d[tid] - m * a;
  }
  __syncthreads();
  ZERO4(a0) ZERO4(a1)
  const int c0 = cq * 64;
  #pragma unroll 8
  for (int c = c0; c < c0 + 64; ++c) {
    float t = fmaf(H[(size_t)c * VOXN + n], As[c], Bs[c]);
    const float4* wk = (const float4*)(w4t + c * 8);
    float4 w;
    w = wk[0]; FMA4(a0, w, t)
    w = wk[1]; FMA4(a1, w, t)
  }
  if (cq > 0) {
    part[cq - 1][vox][0] = a0.x; part[cq - 1][vox][1] = a0.y;
    part[cq - 1][vox][2] = a0.z; part[cq - 1][vox][3] = a0.w;
    part[cq - 1][vox][4] = a1.x; part[cq - 1][vox][5] = a1.y;
    part[cq - 1][vox][6] = a1.z; part[cq - 1][vox][7] = a1.w;
  }
  __syncthreads();
  if (cq == 0) {
    float r0 = a0.x + part[0][vox][0] + part[1][vox][0] + part[2][vox][0];
    float r1 = a0.y + part[0][vox][1] + part[1][vox][1] + part[2][vox][1];
    float r2 = a0.z + part[0][vox][2] + part[1][vox][2] + part[2][vox][2];
    float r3 = a0.w + part[0][vox][3] + part[1][vox][3] + part[2][vox][3];
    float r4 = a1.x + part[0][vox][4] + part[1][vox][4] + part[2][vox][4];
    float r5 = a1.y + part[0][vox][5] + part[1][vox][5] + part[2][vox][5];
    float r6 = a1.z + part[0][vox][6] + part[1][vox][6] + part[2][vox][6];
    float r7 = a1.w + part[0][vox][7] + part[1][vox][7] + part[2][vox][7];
    out[(size_t)0 * VOXN + n] = 1.f / (1.f + expf(-(r0 + b4[0])));
    out[(size_t)1 * VOXN + n] = 1.f / (1.f + expf(-(r1 + b4[1])));
    out[(size_t)2 * VOXN + n] = 1.f / (1.f + expf(-(r2 + b4[2])));
    out[(size_t)3 * VOXN + n] = 1.f / (1.f + expf(-(r3 + b4[3])));
    out[(size_t)4 * VOXN + n] = 1.f / (1.f + expf(-(r4 + b4[4])));
    out[(size_t)5 * VOXN + n] = 1.f / (1.f + expf(-(r5 + b4[5])));
    out[(size_t)6 * VOXN + n] = 1.f / (1.f + expf(-(r6 + b4[6])));
    out[(size_t)7 * VOXN + n] = 1.f / (1.f + expf(-(r7 + b4[7])));
  }
}

extern "C" void kernel_launch(void* const* d_in, const int* in_sizes, int n_in,
                              void* d_out, int out_size, void* d_ws, size_t ws_size,
                              hipStream_t stream)
{
  const float* images  = (const float*)d_in[0];
  const float* offset1 = (const float*)d_in[1];
  const float* w1  = (const float*)d_in[2];
  const float* g1  = (const float*)d_in[3];
  const float* b1  = (const float*)d_in[4];
  const float* w2  = (const float*)d_in[5];
  const float* g2  = (const float*)d_in[6];
  const float* b2  = (const float*)d_in[7];
  const float* w3a = (const float*)d_in[8];
  const float* w3b = (const float*)d_in[9];
  const float* w3c = (const float*)d_in[10];
  const float* w3d = (const float*)d_in[11];
  const float* g3a = (const float*)d_in[12];
  const float* b3a = (const float*)d_in[13];
  const float* g3b = (const float*)d_in[14];
  const float* b3b = (const float*)d_in[15];
  const float* g3c = (const float*)d_in[16];
  const float* b3c = (const float*)d_in[17];
  const float* g3d = (const float*)d_in[18];
  const float* b3d = (const float*)d_in[19];
  const float* w4  = (const float*)d_in[20];
  const float* b4  = (const float*)d_in[21];

  float* ws  = (float*)d_ws;
  float* out = (float*)d_out;

  float* statsY = ws + OFF_STATS_Y;
  float* statsX = ws + OFF_STATS_X2P;
  float* statsH = ws + OFF_STATS_H;
  float* YH     = ws + OFF_YH;   // y, later H
  float* x2p    = ws + OFF_X2P;

  s0a_setup<<<dim3(256), dim3(256), 0, stream>>>(images, offset1, w3a, w3b, w3c, w3d, w4, ws);
  s0b_rank<<<dim3(4), dim3(256), 0, stream>>>(ws);
  s0c_build<<<dim3(64), dim3(256), 0, stream>>>(offset1, w1, w2, ws);
  s1_gather_gemm<<<dim3(512, 4), dim3(256), 0, stream>>>(
      (const uint4*)(ws + OFF_PVOLB), ws + OFF_TPAR,
      (const float4*)(ws + OFF_W1A), YH, statsY);
  s2_bn_gemm<<<dim3(512), dim3(512), 0, stream>>>(
      YH, statsY, g1, b1, (const float4*)(ws + OFF_W2A), x2p, statsX);
  s3_x2_ha<<<dim3(128, 8), dim3(256), 0, stream>>>(x2p, statsX, g2, b2, ws + OFF_W3AT, YH, statsH);
  s_dense<160><<<dim3(128, 8), dim3(256), 0, stream>>>(YH, statsH, g3a, b3a, ws + OFF_W3BT, YH, statsH, 160);
  s_dense<192><<<dim3(128, 8), dim3(256), 0, stream>>>(YH, statsH, g3b, b3b, ws + OFF_W3CT, YH, statsH, 192);
  s_dense<224><<<dim3(128, 8), dim3(256), 0, stream>>>(YH, statsH, g3c, b3c, ws + OFF_W3DT, YH, statsH, 224);
  s7_final<<<dim3(512), dim3(256), 0, stream>>>(YH, statsH, g3d, b3d, ws + OFF_W4T, b4, out);
}

// Round 17
// 326.406 us; speedup vs baseline: 1.3082x; 1.1786x over previous
//
#include <hip/hip_runtime.h>
#include <math.h>

#define VOXN 32768

typedef __attribute__((ext_vector_type(8))) short bf16x8;
typedef __attribute__((ext_vector_type(4))) float f32x4;

// ---- workspace layout (float offsets) ----
constexpr int OFF_STATS_Y   = 0;        // 512
constexpr int OFF_STATS_X2P = 512;      // 256
constexpr int OFF_STATS_H   = 768;      // 512
constexpr int OFF_TPAR      = 1280;     // 1024*16 packed tap params (SORTED order)
constexpr int OFF_W1A       = 17664;    // 32768: bf16 A-frags for w1
constexpr int OFF_W2A       = 83200;    // 16384: bf16 A-frags for w2 (M=128,K=256)
constexpr int OFF_W3AT      = 115968;   // 4096
constexpr int OFF_W3BT      = 120064;   // 5120
constexpr int OFF_W3CT      = 125184;   // 6144
constexpr int OFF_W3DT      = 131328;   // 7168
constexpr int OFF_W4T       = 138496;   // 2048
constexpr int OFF_YH        = 140544;   // 8388608 (y, later H)
constexpr int OFF_C0A       = OFF_YH;       // 1024 ints (dead before s1 writes y)
constexpr int OFF_PERM      = OFF_YH + 1024;// 1024 ints
constexpr int OFF_X2P       = 8529152;  // 4194304 (x2pre; ALSO hosts pvolB early)
constexpr int OFF_PVOLB     = OFF_X2P;  // 941192 uint4 (8 bf16 cube)

#define FMA4(A, W, X) { (A).x = fmaf((W).x, (X), (A).x); (A).y = fmaf((W).y, (X), (A).y); \
                        (A).z = fmaf((W).z, (X), (A).z); (A).w = fmaf((W).w, (X), (A).w); }
#define RELU4(A) { (A).x = fmaxf((A).x, 0.f); (A).y = fmaxf((A).y, 0.f); \
                   (A).z = fmaxf((A).z, 0.f); (A).w = fmaxf((A).w, 0.f); }
#define ZERO4(A) float4 A; (A).x = 0.f; (A).y = 0.f; (A).z = 0.f; (A).w = 0.f;

#define BFLY(s, q) { s += __shfl_xor(s, 32, 64); q += __shfl_xor(q, 32, 64); \
                     s += __shfl_xor(s, 16, 64); q += __shfl_xor(q, 16, 64); \
                     s += __shfl_xor(s,  8, 64); q += __shfl_xor(q,  8, 64); \
                     s += __shfl_xor(s,  4, 64); q += __shfl_xor(q,  4, 64); \
                     s += __shfl_xor(s,  2, 64); q += __shfl_xor(q,  2, 64); \
                     s += __shfl_xor(s,  1, 64); q += __shfl_xor(q,  1, 64); }
#define STASH1(V, O) { float s_ = (V), q_ = (V) * (V); BFLY(s_, q_) \
                       if (lane == (O)) { ms = s_; mq = q_; } }
#define STASH4(A, O0) STASH1((A).x, (O0)+0) STASH1((A).y, (O0)+1) \
                      STASH1((A).z, (O0)+2) STASH1((A).w, (O0)+3)

__device__ __forceinline__ unsigned short f2bf(float f) {
  unsigned int u = __float_as_uint(f);
  u += 0x7FFFu + ((u >> 16) & 1u);     // RNE
  return (unsigned short)(u >> 16);
}

__device__ __forceinline__ float corner(const float* __restrict__ im, int x, int y, int z) {
  if (x >= 33 && x < 65 && y >= 33 && y < 65 && z >= 33 && z < 65)
    return im[((z - 33) * 32 + (y - 33)) * 32 + (x - 33)];
  return 0.f;
}

__device__ __forceinline__ int tap_c0(const float* __restrict__ offset1, int k, int s) {
  float ox = fminf(fmaxf(offset1[k * 6 + s * 3 + 0] * 16.f, -1000.f), 1000.f);
  float oy = fminf(fmaxf(offset1[k * 6 + s * 3 + 1] * 16.f, -1000.f), 1000.f);
  float oz = fminf(fmaxf(offset1[k * 6 + s * 3 + 2] * 16.f, -1000.f), 1000.f);
  int sx = (int)floorf(ox), sy = (int)floorf(oy), sz = (int)floorf(oz);
  bool valid = (sx >= -33 && sx <= 32) && (sy >= -33 && sy <= 32) && (sz >= -33 && sz <= 32);
  if (!valid) { sx = sy = sz = 0; }
  return (sz + 33) * 9604 + (sy + 33) * 98 + (sx + 33);
}

// ---------------- S0a: bf16 cube volume (predicated fast fill) + keys + transposes ------
__global__ void s0a_setup(const float* __restrict__ images, const float* __restrict__ offset1,
                          const float* __restrict__ w3a, const float* __restrict__ w3b,
                          const float* __restrict__ w3c, const float* __restrict__ w3d,
                          const float* __restrict__ w4, float* __restrict__ ws)
{
  const int idx = blockIdx.x * blockDim.x + threadIdx.x;
  const int stride = gridDim.x * blockDim.x;
  for (int i = idx; i < 1280; i += stride) ws[i] = 0.f;
  uint4* qq = (uint4*)(ws + OFF_PVOLB);
  for (int i = idx; i < 941192; i += stride) {
    int x = i % 98, t = i / 98, y = t % 98, z = t / 98;
    uint4 f; f.x = 0u; f.y = 0u; f.z = 0u; f.w = 0u;
    if (x >= 32 && x <= 64 && y >= 32 && y <= 64 && z >= 32 && z <= 64) {
      float c000 = corner(images, x, y, z),     c100 = corner(images, x+1, y, z);
      float c010 = corner(images, x, y+1, z),   c110 = corner(images, x+1, y+1, z);
      float c001 = corner(images, x, y, z+1),   c101 = corner(images, x+1, y, z+1);
      float c011 = corner(images, x, y+1, z+1), c111 = corner(images, x+1, y+1, z+1);
      f.x = (unsigned int)f2bf(c000) | ((unsigned int)f2bf(c100) << 16);
      f.y = (unsigned int)f2bf(c010) | ((unsigned int)f2bf(c110) << 16);
      f.z = (unsigned int)f2bf(c001) | ((unsigned int)f2bf(c101) << 16);
      f.w = (unsigned int)f2bf(c011) | ((unsigned int)f2bf(c111) << 16);
    }
    qq[i] = f;
  }
  int* c0a = (int*)(ws + OFF_C0A);
  for (int k = idx; k < 1024; k += stride) c0a[k] = tap_c0(offset1, k, 0);
  for (int i = idx; i < 4096;  i += stride) { int o = i & 31,  c = i >> 5; ws[OFF_W3AT + i] = w3a[o * 128 + c]; }
  for (int i = idx; i < 5120;  i += stride) { int o = i & 31,  c = i >> 5; ws[OFF_W3BT + i] = w3b[o * 160 + c]; }
  for (int i = idx; i < 6144;  i += stride) { int o = i & 31,  c = i >> 5; ws[OFF_W3CT + i] = w3c[o * 192 + c]; }
  for (int i = idx; i < 7168;  i += stride) { int o = i & 31,  c = i >> 5; ws[OFF_W3DT + i] = w3d[o * 224 + c]; }
  for (int i = idx; i < 2048;  i += stride) { int l = i & 7,   c = i >> 3; ws[OFF_W4T + i] = w4[l * 256 + c]; }
}

// ---------------- S0b: rank-sort taps by c0 within each group ----------------
__global__ void s0b_rank(float* __restrict__ ws)
{
  const int idx = blockIdx.x * blockDim.x + threadIdx.x;
  if (idx >= 1024) return;
  const int g = idx >> 8, k = idx & 255;
  const int* c0a = (const int*)(ws + OFF_C0A);
  int* perm = (int*)(ws + OFF_PERM);
  const int my = c0a[g * 256 + k];
  int rank = 0;
  for (int j = 0; j < 256; ++j) {
    int cj = c0a[g * 256 + j];
    rank += (cj < my) || (cj == my && j < k);
  }
  perm[g * 256 + rank] = k;
}

// ---------------- S0c: permuted tap params + bf16 A-frag packs (w1, w2) ----------------
__global__ void s0c_build(const float* __restrict__ offset1, const float* __restrict__ w1,
                          const float* __restrict__ w2, float* __restrict__ ws)
{
  const int idx = blockIdx.x * blockDim.x + threadIdx.x;
  const int stride = gridDim.x * blockDim.x;
  const int* perm = (const int*)(ws + OFF_PERM);
  for (int p = idx; p < 1024; p += stride) {
    const int g = p >> 8;
    const int k = g * 256 + perm[p];
    float* tp = ws + OFF_TPAR + p * 16;
    for (int s = 0; s < 2; ++s) {
      float ox = fminf(fmaxf(offset1[k * 6 + s * 3 + 0] * 16.f, -1000.f), 1000.f);
      float oy = fminf(fmaxf(offset1[k * 6 + s * 3 + 1] * 16.f, -1000.f), 1000.f);
      float oz = fminf(fmaxf(offset1[k * 6 + s * 3 + 2] * 16.f, -1000.f), 1000.f);
      float fxf = floorf(ox), fyf = floorf(oy), fzf = floorf(oz);
      float fx = ox - fxf, fy = oy - fyf, fz = oz - fzf;
      int sx = (int)fxf, sy = (int)fyf, sz = (int)fzf;
      bool valid = (sx >= -33 && sx <= 32) && (sy >= -33 && sy <= 32) && (sz >= -33 && sz <= 32);
      if (!valid) { sx = sy = sz = 0; }
      float vm = valid ? 1.f : 0.f;
      int c0 = (sz + 33) * 9604 + (sy + 33) * 98 + (sx + 33);
      float sgn = s ? -1.f : 1.f;
      float wy0 = 1.f - fy, wy1 = fy, wz0 = 1.f - fz, wz1 = fz;
      tp[s * 8 + 0] = __int_as_float(c0);
      tp[s * 8 + 1] = vm * (1.f - fx);
      tp[s * 8 + 2] = vm * fx;
      tp[s * 8 + 3] = vm * sgn * wz0 * wy0;
      tp[s * 8 + 4] = vm * sgn * wz0 * wy1;
      tp[s * 8 + 5] = vm * sgn * wz1 * wy0;
      tp[s * 8 + 6] = vm * sgn * wz1 * wy1;
      tp[s * 8 + 7] = 0.f;
    }
  }
  for (int i = idx; i < 32768; i += stride) {
    int jp = i & 3;
    int l  = (i >> 2) & 63;
    int ks = (i >> 8) & 7;
    int mt = (i >> 11) & 3;
    int g  = i >> 13;
    int row = mt * 16 + (l & 15);
    int kbase = g * 256 + ks * 32 + (l >> 4) * 8 + jp * 2;
    int ka = perm[kbase], kb = perm[kbase + 1];
    unsigned short b0 = f2bf(w1[g * 16384 + row * 256 + ka]);
    unsigned short b1 = f2bf(w1[g * 16384 + row * 256 + kb]);
    ws[OFF_W1A + i] = __uint_as_float((unsigned int)b0 | ((unsigned int)b1 << 16));
  }
  for (int i = idx; i < 16384; i += stride) {
    int jp = i & 3;
    int l  = (i >> 2) & 63;
    int ks = (i >> 8) & 7;
    int mt = i >> 11;              // 0..7
    int row = mt * 16 + (l & 15);
    int k = ks * 32 + (l >> 4) * 8 + jp * 2;
    unsigned short b0 = f2bf(w2[row * 256 + k]);
    unsigned short b1 = f2bf(w2[row * 256 + k + 1]);
    ws[OFF_W2A + i] = __uint_as_float((unsigned int)b0 | ((unsigned int)b1 << 16));
  }
}

// one tap from the bf16-cube volume: ONE uint4 load
__device__ __forceinline__ float tapB(const uint4* __restrict__ Q, int vbase,
                                      const float4 t0, const float4 t1)
{
  uint4 c = Q[vbase + __float_as_int(t0.x)];
  float c0 = __uint_as_float(c.x << 16), c1 = __uint_as_float(c.x & 0xffff0000u);
  float c2 = __uint_as_float(c.y << 16), c3 = __uint_as_float(c.y & 0xffff0000u);
  float c4 = __uint_as_float(c.z << 16), c5 = __uint_as_float(c.z & 0xffff0000u);
  float c6 = __uint_as_float(c.w << 16), c7 = __uint_as_float(c.w & 0xffff0000u);
  float h0 = c0 * t0.y + c1 * t0.z;
  float h1 = c2 * t0.y + c3 * t0.z;
  float h2 = c4 * t0.y + c5 * t0.z;
  float h3 = c6 * t0.y + c7 * t0.z;
  return h0 * t0.w + h1 * t1.x + h2 * t1.y + h3 * t1.z;
}

// ---------------- S1: fused gather + MFMA (R14-proven 128-voxel version) ----------------
__global__ __launch_bounds__(256, 4) void s1_gather_gemm(
    const uint4* __restrict__ pvolB, const float* __restrict__ tparP,
    const float4* __restrict__ apack, float* __restrict__ y, float* __restrict__ stats_y)
{
  __shared__ unsigned short xt[128 * 72];   // 18432 B
  const int tid = threadIdx.x;
  const int lane = tid & 63;
  const int wv = tid >> 6;          // m-tile 0..3
  const int g = blockIdx.y;
  const int v0 = blockIdx.x * 128;
  const int n = tid & 127;
  const int khalf = tid >> 7;       // 0/1: k-half of chunk
  const int v = v0 + n;
  const int vbase = (v >> 10) * 9604 + ((v >> 5) & 31) * 98 + (v & 31);
  const float4* tq_base = (const float4*)(tparP + g * 4096);

  f32x4 acc[8];
  #pragma unroll
  for (int i = 0; i < 8; ++i) acc[i] = (f32x4){0.f, 0.f, 0.f, 0.f};

  for (int ch = 0; ch < 4; ++ch) {
    const int kb = ch * 64 + khalf * 32;
    __syncthreads();
    #pragma unroll 2
    for (int i2 = 0; i2 < 32; i2 += 2) {
      const int kt = kb + i2;
      float4 t0 = tq_base[kt*4+0], t1 = tq_base[kt*4+1];
      float4 t2 = tq_base[kt*4+2], t3 = tq_base[kt*4+3];
      float xv0 = tapB(pvolB, vbase, t0, t1) + tapB(pvolB, vbase, t2, t3);
      float4 u0 = tq_base[kt*4+4], u1 = tq_base[kt*4+5];
      float4 u2 = tq_base[kt*4+6], u3 = tq_base[kt*4+7];
      float xv1 = tapB(pvolB, vbase, u0, u1) + tapB(pvolB, vbase, u2, u3);
      unsigned int pk = (unsigned int)f2bf(xv0) | ((unsigned int)f2bf(xv1) << 16);
      *(unsigned int*)&xt[n * 72 + khalf * 32 + i2] = pk;
    }
    __syncthreads();
    #pragma unroll
    for (int s = 0; s < 2; ++s) {
      float4 araw = apack[(((g * 4 + wv) * 8) + ch * 2 + s) * 64 + lane];
      bf16x8 a = *reinterpret_cast<bf16x8*>(&araw);
      #pragma unroll
      for (int nt = 0; nt < 8; ++nt) {
        const unsigned short* bp = &xt[(nt * 16 + (lane & 15)) * 72 + s * 32 + (lane >> 4) * 8];
        float4 braw = *(const float4*)bp;
        bf16x8 b = *reinterpret_cast<bf16x8*>(&braw);
        acc[nt] = __builtin_amdgcn_mfma_f32_16x16x32_bf16(a, b, acc[nt], 0, 0, 0);
      }
    }
  }
  const int obase = g << 6;
  float srow0 = 0.f, srow1 = 0.f, srow2 = 0.f, srow3 = 0.f;
  float qrow0 = 0.f, qrow1 = 0.f, qrow2 = 0.f, qrow3 = 0.f;
  #pragma unroll
  for (int nt = 0; nt < 8; ++nt) {
    const int col = v0 + nt * 16 + (lane & 15);
    const int rbase = obase + wv * 16 + (lane >> 4) * 4;
    float e0 = acc[nt][0], e1 = acc[nt][1], e2 = acc[nt][2], e3 = acc[nt][3];
    y[(size_t)(rbase + 0) * VOXN + col] = e0;
    y[(size_t)(rbase + 1) * VOXN + col] = e1;
    y[(size_t)(rbase + 2) * VOXN + col] = e2;
    y[(size_t)(rbase + 3) * VOXN + col] = e3;
    srow0 += e0; qrow0 += e0 * e0;
    srow1 += e1; qrow1 += e1 * e1;
    srow2 += e2; qrow2 += e2 * e2;
    srow3 += e3; qrow3 += e3 * e3;
  }
  #define ROWRED(S, Q, R) { \
    float s_ = S, q_ = Q; \
    s_ += __shfl_xor(s_, 1, 64); q_ += __shfl_xor(q_, 1, 64); \
    s_ += __shfl_xor(s_, 2, 64); q_ += __shfl_xor(q_, 2, 64); \
    s_ += __shfl_xor(s_, 4, 64); q_ += __shfl_xor(q_, 4, 64); \
    s_ += __shfl_xor(s_, 8, 64); q_ += __shfl_xor(q_, 8, 64); \
    if ((lane & 15) == 0) { \
      int row = obase + wv * 16 + (lane >> 4) * 4 + (R); \
      atomicAdd(&stats_y[row], s_); atomicAdd(&stats_y[256 + row], q_); } }
  ROWRED(srow0, qrow0, 0) ROWRED(srow1, qrow1, 1)
  ROWRED(srow2, qrow2, 2) ROWRED(srow3, qrow3, 3)
  #undef ROWRED
}

// ---------------- S2: x1 = relu(BN(y)) -> bf16 -> MFMA vs w2, 64-output halves ----------
// 256 thr = 4 waves; 128 voxels; 64 outputs (half = blockIdx.y). grid (256,2) =
// 512 blocks = 2 blocks/CU = 16 waves/CU. Mirrors s1's proven skeleton.
__global__ __launch_bounds__(256) void s2_bn_gemm(
    const float* __restrict__ y, const float* __restrict__ stats_y,
    const float* __restrict__ g1, const float* __restrict__ b1,
    const float4* __restrict__ w2a, float* __restrict__ x2p, float* __restrict__ stats_x2p)
{
  __shared__ float As[256], Bs[256];
  __shared__ unsigned short xt[128 * 72];   // 18432 B
  const int tid = threadIdx.x;
  const int lane = tid & 63;
  const int wv = tid >> 6;          // m-tile within half (0..3)
  const int n = tid & 127;
  const int khalf = tid >> 7;       // k-half of chunk
  const int half = blockIdx.y;      // 0/1: output half
  const int v0 = blockIdx.x * 128;
  const int v = v0 + n;
  {
    float m = stats_y[tid] * (1.f / VOXN);
    float vv = stats_y[256 + tid] * (1.f / VOXN) - m * m;
    float a = g1[tid] * rsqrtf(vv + 1e-5f);
    As[tid] = a; Bs[tid] = b1[tid] - m * a;
  }
  f32x4 acc[8];
  #pragma unroll
  for (int i = 0; i < 8; ++i) acc[i] = (f32x4){0.f, 0.f, 0.f, 0.f};

  for (int ch = 0; ch < 4; ++ch) {
    const int kb = ch * 64 + khalf * 32;
    __syncthreads();
    #pragma unroll 2
    for (int i2 = 0; i2 < 32; i2 += 2) {
      const int c = kb + i2;
      float t0 = fmaxf(fmaf(y[(size_t)c * VOXN + v], As[c], Bs[c]), 0.f);
      float t1 = fmaxf(fmaf(y[(size_t)(c + 1) * VOXN + v], As[c + 1], Bs[c + 1]), 0.f);
      unsigned int pk = (unsigned int)f2bf(t0) | ((unsigned int)f2bf(t1) << 16);
      *(unsigned int*)&xt[n * 72 + khalf * 32 + i2] = pk;
    }
    __syncthreads();
    #pragma unroll
    for (int s = 0; s < 2; ++s) {
      float4 araw = w2a[(((half * 4 + wv) * 8) + ch * 2 + s) * 64 + lane];
      bf16x8 a = *reinterpret_cast<bf16x8*>(&araw);
      #pragma unroll
      for (int nt = 0; nt < 8; ++nt) {
        const unsigned short* bp = &xt[(nt * 16 + (lane & 15)) * 72 + s * 32 + (lane >> 4) * 8];
        float4 braw = *(const float4*)bp;
        bf16x8 b = *reinterpret_cast<bf16x8*>(&braw);
        acc[nt] = __builtin_amdgcn_mfma_f32_16x16x32_bf16(a, b, acc[nt], 0, 0, 0);
      }
    }
  }
  const int mbase = half * 64 + wv * 16;
  float srow0 = 0.f, srow1 = 0.f, srow2 = 0.f, srow3 = 0.f;
  float qrow0 = 0.f, qrow1 = 0.f, qrow2 = 0.f, qrow3 = 0.f;
  #pragma unroll
  for (int nt = 0; nt < 8; ++nt) {
    const int col = v0 + nt * 16 + (lane & 15);
    const int rbase = mbase + (lane >> 4) * 4;
    float e0 = acc[nt][0], e1 = acc[nt][1], e2 = acc[nt][2], e3 = acc[nt][3];
    x2p[(size_t)(rbase + 0) * VOXN + col] = e0;
    x2p[(size_t)(rbase + 1) * VOXN + col] = e1;
    x2p[(size_t)(rbase + 2) * VOXN + col] = e2;
    x2p[(size_t)(rbase + 3) * VOXN + col] = e3;
    srow0 += e0; qrow0 += e0 * e0;
    srow1 += e1; qrow1 += e1 * e1;
    srow2 += e2; qrow2 += e2 * e2;
    srow3 += e3; qrow3 += e3 * e3;
  }
  #define ROWRED2(S, Q, R) { \
    float s_ = S, q_ = Q; \
    s_ += __shfl_xor(s_, 1, 64); q_ += __shfl_xor(q_, 1, 64); \
    s_ += __shfl_xor(s_, 2, 64); q_ += __shfl_xor(q_, 2, 64); \
    s_ += __shfl_xor(s_, 4, 64); q_ += __shfl_xor(q_, 4, 64); \
    s_ += __shfl_xor(s_, 8, 64); q_ += __shfl_xor(q_, 8, 64); \
    if ((lane & 15) == 0) { \
      int row = mbase + (lane >> 4) * 4 + (R); \
      atomicAdd(&stats_x2p[row], s_); atomicAdd(&stats_x2p[128 + row], q_); } }
  ROWRED2(srow0, qrow0, 0) ROWRED2(srow1, qrow1, 1)
  ROWRED2(srow2, qrow2, 2) ROWRED2(srow3, qrow3, 3)
  #undef ROWRED2
}

// ---------------- S3: x2 = BN(x2pre) -> H[0:128]; ha -> H[128+qh*4 ..] (8-way split) ----
__global__ __launch_bounds__(256) void s3_x2_ha(
    const float* __restrict__ x2p, const float* __restrict__ stats_x2p,
    const float* __restrict__ g2, const float* __restrict__ b2,
    const float* __restrict__ w3at, float* __restrict__ H, float* __restrict__ stats_H)
{
  __shared__ float As[128], Bs[128];
  __shared__ float redS[4][4], redQ[4][4];
  const int tid = threadIdx.x;
  const int lane = tid & 63;
  const int wv = tid >> 6;
  if (tid < 128) {
    float m = stats_x2p[tid] * (1.f / VOXN);
    float vv = stats_x2p[128 + tid] * (1.f / VOXN) - m * m;
    float a = g2[tid] * rsqrtf(vv + 1e-5f);
    As[tid] = a; Bs[tid] = b2[tid] - m * a;
    if (blockIdx.x == 0 && blockIdx.y == 0) {
      float mean = b2[tid];
      float var = a * a * vv;
      stats_H[tid] = mean * (float)VOXN;
      stats_H[256 + tid] = (var + mean * mean) * (float)VOXN;
    }
  }
  __syncthreads();
  const int qh = blockIdx.y;           // 0..7 -> 4 outputs
  const int n = blockIdx.x * 256 + tid;
  ZERO4(a0)
  #pragma unroll 8
  for (int c = 0; c < 128; ++c) {
    float x2v = fmaf(x2p[(size_t)c * VOXN + n], As[c], Bs[c]);
    if (qh == 0) H[(size_t)c * VOXN + n] = x2v;
    const float4* wk = (const float4*)(w3at + c * 32 + qh * 4);
    float4 w = wk[0];
    FMA4(a0, w, x2v)
  }
  RELU4(a0)
  const int ob = 128 + qh * 4;
  H[((size_t)(ob + 0)) * VOXN + n] = a0.x;
  H[((size_t)(ob + 1)) * VOXN + n] = a0.y;
  H[((size_t)(ob + 2)) * VOXN + n] = a0.z;
  H[((size_t)(ob + 3)) * VOXN + n] = a0.w;
  float ms = 0.f, mq = 0.f;
  STASH4(a0, 0)
  if (lane < 4) { redS[wv][lane] = ms; redQ[wv][lane] = mq; }
  __syncthreads();
  if (tid < 4) {
    float s = redS[0][tid] + redS[1][tid] + redS[2][tid] + redS[3][tid];
    float qq = redQ[0][tid] + redQ[1][tid] + redQ[2][tid] + redQ[3][tid];
    atomicAdd(&stats_H[ob + tid], s);
    atomicAdd(&stats_H[256 + ob + tid], qq);
  }
}

// ---------------- S4/5/6: h = relu(w @ BN(H[0:CIN])) -> H[och + qh*4 ..] (8-way) ----------
template<int CIN>
__global__ __launch_bounds__(256) void s_dense(
    const float* __restrict__ Hin, const float* __restrict__ stats_H,
    const float* __restrict__ g, const float* __restrict__ b,
    const float* __restrict__ wt, float* __restrict__ H, float* __restrict__ stats_out, int och)
{
  __shared__ float As[CIN], Bs[CIN];
  __shared__ float redS[4][4], redQ[4][4];
  const int tid = threadIdx.x;
  const int lane = tid & 63;
  const int wv = tid >> 6;
  if (tid < CIN) {
    float m = stats_H[tid] * (1.f / VOXN);
    float vv = stats_H[256 + tid] * (1.f / VOXN) - m * m;
    float a = g[tid] * rsqrtf(vv + 1e-5f);
    As[tid] = a; Bs[tid] = b[tid] - m * a;
  }
  __syncthreads();
  const int osub = blockIdx.y * 4;     // 0..7 -> 4 outputs
  const int n = blockIdx.x * 256 + tid;
  ZERO4(a0)
  #pragma unroll 8
  for (int c = 0; c < CIN; ++c) {
    float t = fmaf(Hin[(size_t)c * VOXN + n], As[c], Bs[c]);
    const float4* wk = (const float4*)(wt + c * 32 + osub);
    float4 w = wk[0];
    FMA4(a0, w, t)
  }
  RELU4(a0)
  const int ob = och + osub;
  H[((size_t)(ob + 0)) * VOXN + n] = a0.x;
  H[((size_t)(ob + 1)) * VOXN + n] = a0.y;
  H[((size_t)(ob + 2)) * VOXN + n] = a0.z;
  H[((size_t)(ob + 3)) * VOXN + n] = a0.w;
  float ms = 0.f, mq = 0.f;
  STASH4(a0, 0)
  if (lane < 4) { redS[wv][lane] = ms; redQ[wv][lane] = mq; }
  __syncthreads();
  if (tid < 4) {
    float s = redS[0][tid] + redS[1][tid] + redS[2][tid] + redS[3][tid];
    float qq = redQ[0][tid] + redQ[1][tid] + redQ[2][tid] + redQ[3][tid];
    atomicAdd(&stats_out[ob + tid], s);
    atomicAdd(&stats_out[256 + ob + tid], qq);
  }
}

// ---------------- S7: 256 thr = 64 vox x 4 c-quarters; LDS combine; grid 512 ------------
__global__ __launch_bounds__(256) void s7_final(
    const float* __restrict__ H, const float* __restrict__ stats_H,
    const float* __restrict__ g3d, const float* __restrict__ b3d,
    const float* __restrict__ w4t, const float* __restrict__ b4, float* __restrict__ out)
{
  __shared__ float As[256], Bs[256];
  __shared__ float part[3][64][8];
  const int tid = threadIdx.x;
  const int vox = tid & 63;
  const int cq = tid >> 6;              // c-quarter 0..3
  const int n = blockIdx.x * 64 + vox;
  {
    float m = stats_H[tid] * (1.f / VOXN);
    float vv = stats_H[256 + tid] * (1.f / VOXN) - m * m;
    float a = g3d[tid] * rsqrtf(vv + 1e-5f);
    As[tid] = a; Bs[tid] = b3d[tid] - m * a;
  }
  __syncthreads();
  ZERO4(a0) ZERO4(a1)
  const int c0 = cq * 64;
  #pragma unroll 8
  for (int c = c0; c < c0 + 64; ++c) {
    float t = fmaf(H[(size_t)c * VOXN + n], As[c], Bs[c]);
    const float4* wk = (const float4*)(w4t + c * 8);
    float4 w;
    w = wk[0]; FMA4(a0, w, t)
    w = wk[1]; FMA4(a1, w, t)
  }
  if (cq > 0) {
    part[cq - 1][vox][0] = a0.x; part[cq - 1][vox][1] = a0.y;
    part[cq - 1][vox][2] = a0.z; part[cq - 1][vox][3] = a0.w;
    part[cq - 1][vox][4] = a1.x; part[cq - 1][vox][5] = a1.y;
    part[cq - 1][vox][6] = a1.z; part[cq - 1][vox][7] = a1.w;
  }
  __syncthreads();
  if (cq == 0) {
    float r0 = a0.x + part[0][vox][0] + part[1][vox][0] + part[2][vox][0];
    float r1 = a0.y + part[0][vox][1] + part[1][vox][1] + part[2][vox][1];
    float r2 = a0.z + part[0][vox][2] + part[1][vox][2] + part[2][vox][2];
    float r3 = a0.w + part[0][vox][3] + part[1][vox][3] + part[2][vox][3];
    float r4 = a1.x + part[0][vox][4] + part[1][vox][4] + part[2][vox][4];
    float r5 = a1.y + part[0][vox][5] + part[1][vox][5] + part[2][vox][5];
    float r6 = a1.z + part[0][vox][6] + part[1][vox][6] + part[2][vox][6];
    float r7 = a1.w + part[0][vox][7] + part[1][vox][7] + part[2][vox][7];
    out[(size_t)0 * VOXN + n] = 1.f / (1.f + expf(-(r0 + b4[0])));
    out[(size_t)1 * VOXN + n] = 1.f / (1.f + expf(-(r1 + b4[1])));
    out[(size_t)2 * VOXN + n] = 1.f / (1.f + expf(-(r2 + b4[2])));
    out[(size_t)3 * VOXN + n] = 1.f / (1.f + expf(-(r3 + b4[3])));
    out[(size_t)4 * VOXN + n] = 1.f / (1.f + expf(-(r4 + b4[4])));
    out[(size_t)5 * VOXN + n] = 1.f / (1.f + expf(-(r5 + b4[5])));
    out[(size_t)6 * VOXN + n] = 1.f / (1.f + expf(-(r6 + b4[6])));
    out[(size_t)7 * VOXN + n] = 1.f / (1.f + expf(-(r7 + b4[7])));
  }
}

extern "C" void kernel_launch(void* const* d_in, const int* in_sizes, int n_in,
                              void* d_out, int out_size, void* d_ws, size_t ws_size,
                              hipStream_t stream)
{
  const float* images  = (const float*)d_in[0];
  const float* offset1 = (const float*)d_in[1];
  const float* w1  = (const float*)d_in[2];
  const float* g1  = (const float*)d_in[3];
  const float* b1  = (const float*)d_in[4];
  const float* w2  = (const float*)d_in[5];
  const float* g2  = (const float*)d_in[6];
  const float* b2  = (const float*)d_in[7];
  const float* w3a = (const float*)d_in[8];
  const float* w3b = (const float*)d_in[9];
  const float* w3c = (const float*)d_in[10];
  const float* w3d = (const float*)d_in[11];
  const float* g3a = (const float*)d_in[12];
  const float* b3a = (const float*)d_in[13];
  const float* g3b = (const float*)d_in[14];
  const float* b3b = (const float*)d_in[15];
  const float* g3c = (const float*)d_in[16];
  const float* b3c = (const float*)d_in[17];
  const float* g3d = (const float*)d_in[18];
  const float* b3d = (const float*)d_in[19];
  const float* w4  = (const float*)d_in[20];
  const float* b4  = (const float*)d_in[21];

  float* ws  = (float*)d_ws;
  float* out = (float*)d_out;

  float* statsY = ws + OFF_STATS_Y;
  float* statsX = ws + OFF_STATS_X2P;
  float* statsH = ws + OFF_STATS_H;
  float* YH     = ws + OFF_YH;   // y, later H
  float* x2p    = ws + OFF_X2P;

  s0a_setup<<<dim3(256), dim3(256), 0, stream>>>(images, offset1, w3a, w3b, w3c, w3d, w4, ws);
  s0b_rank<<<dim3(4), dim3(256), 0, stream>>>(ws);
  s0c_build<<<dim3(64), dim3(256), 0, stream>>>(offset1, w1, w2, ws);
  s1_gather_gemm<<<dim3(256, 4), dim3(256), 0, stream>>>(
      (const uint4*)(ws + OFF_PVOLB), ws + OFF_TPAR,
      (const float4*)(ws + OFF_W1A), YH, statsY);
  s2_bn_gemm<<<dim3(256, 2), dim3(256), 0, stream>>>(
      YH, statsY, g1, b1, (const float4*)(ws + OFF_W2A), x2p, statsX);
  s3_x2_ha<<<dim3(128, 8), dim3(256), 0, stream>>>(x2p, statsX, g2, b2, ws + OFF_W3AT, YH, statsH);
  s_dense<160><<<dim3(128, 8), dim3(256), 0, stream>>>(YH, statsH, g3a, b3a, ws + OFF_W3BT, YH, statsH, 160);
  s_dense<192><<<dim3(128, 8), dim3(256), 0, stream>>>(YH, statsH, g3b, b3b, ws + OFF_W3CT, YH, statsH, 192);
  s_dense<224><<<dim3(128, 8), dim3(256), 0, stream>>>(YH, statsH, g3c, b3c, ws + OFF_W3DT, YH, statsH, 224);
  s7_final<<<dim3(512), dim3(256), 0, stream>>>(YH, statsH, g3d, b3d, ws + OFF_W4T, b4, out);
}

// Round 18
// 311.967 us; speedup vs baseline: 1.3688x; 1.0463x over previous
//
#include <hip/hip_runtime.h>
#include <math.h>

#define VOXN 32768

typedef __attribute__((ext_vector_type(8))) short bf16x8;
typedef __attribute__((ext_vector_type(4))) float f32x4;

// ---- workspace layout (float offsets) ----
constexpr int OFF_STATS_Y   = 0;        // 512
constexpr int OFF_STATS_X2P = 512;      // 256
constexpr int OFF_STATS_H   = 768;      // 512 (only [128,256) + [384,512) used)
constexpr int OFF_TPAR      = 1280;     // 1024*16 packed tap params (SORTED order)
constexpr int OFF_W1A       = 17664;    // 32768: bf16 A-frags for w1
constexpr int OFF_W2A       = 83200;    // 16384: bf16 A-frags for w2 (M=128,K=256)
constexpr int OFF_W3AT      = 115968;   // 4096
constexpr int OFF_W3BT      = 120064;   // 5120
constexpr int OFF_W3CT      = 125184;   // 6144
constexpr int OFF_W3DT      = 131328;   // 7168
constexpr int OFF_W4T       = 138496;   // 2048
constexpr int OFF_YH        = 140544;   // 8388608 (y, later H[128:256))
constexpr int OFF_C0A       = OFF_YH;       // 1024 ints (dead before s1 writes y)
constexpr int OFF_PERM      = OFF_YH + 1024;// 1024 ints
constexpr int OFF_X2P       = 8529152;  // 4194304 (x2pre; ALSO hosts pvolB early)
constexpr int OFF_PVOLB     = OFF_X2P;  // 941192 uint4 (8 bf16 cube)

#define FMA4(A, W, X) { (A).x = fmaf((W).x, (X), (A).x); (A).y = fmaf((W).y, (X), (A).y); \
                        (A).z = fmaf((W).z, (X), (A).z); (A).w = fmaf((W).w, (X), (A).w); }
#define RELU4(A) { (A).x = fmaxf((A).x, 0.f); (A).y = fmaxf((A).y, 0.f); \
                   (A).z = fmaxf((A).z, 0.f); (A).w = fmaxf((A).w, 0.f); }
#define ZERO4(A) float4 A; (A).x = 0.f; (A).y = 0.f; (A).z = 0.f; (A).w = 0.f;

#define BFLY(s, q) { s += __shfl_xor(s, 32, 64); q += __shfl_xor(q, 32, 64); \
                     s += __shfl_xor(s, 16, 64); q += __shfl_xor(q, 16, 64); \
                     s += __shfl_xor(s,  8, 64); q += __shfl_xor(q,  8, 64); \
                     s += __shfl_xor(s,  4, 64); q += __shfl_xor(q,  4, 64); \
                     s += __shfl_xor(s,  2, 64); q += __shfl_xor(q,  2, 64); \
                     s += __shfl_xor(s,  1, 64); q += __shfl_xor(q,  1, 64); }
#define STASH1(V, O) { float s_ = (V), q_ = (V) * (V); BFLY(s_, q_) \
                       if (lane == (O)) { ms = s_; mq = q_; } }
#define STASH4(A, O0) STASH1((A).x, (O0)+0) STASH1((A).y, (O0)+1) \
                      STASH1((A).z, (O0)+2) STASH1((A).w, (O0)+3)

__device__ __forceinline__ unsigned short f2bf(float f) {
  unsigned int u = __float_as_uint(f);
  u += 0x7FFFu + ((u >> 16) & 1u);     // RNE
  return (unsigned short)(u >> 16);
}

__device__ __forceinline__ float corner(const float* __restrict__ im, int x, int y, int z) {
  if (x >= 33 && x < 65 && y >= 33 && y < 65 && z >= 33 && z < 65)
    return im[((z - 33) * 32 + (y - 33)) * 32 + (x - 33)];
  return 0.f;
}

__device__ __forceinline__ int tap_c0(const float* __restrict__ offset1, int k, int s) {
  float ox = fminf(fmaxf(offset1[k * 6 + s * 3 + 0] * 16.f, -1000.f), 1000.f);
  float oy = fminf(fmaxf(offset1[k * 6 + s * 3 + 1] * 16.f, -1000.f), 1000.f);
  float oz = fminf(fmaxf(offset1[k * 6 + s * 3 + 2] * 16.f, -1000.f), 1000.f);
  int sx = (int)floorf(ox), sy = (int)floorf(oy), sz = (int)floorf(oz);
  bool valid = (sx >= -33 && sx <= 32) && (sy >= -33 && sy <= 32) && (sz >= -33 && sz <= 32);
  if (!valid) { sx = sy = sz = 0; }
  return (sz + 33) * 9604 + (sy + 33) * 98 + (sx + 33);
}

// ---------------- S0a: bf16 cube volume (predicated fast fill) + keys + transposes ------
__global__ void s0a_setup(const float* __restrict__ images, const float* __restrict__ offset1,
                          const float* __restrict__ w3a, const float* __restrict__ w3b,
                          const float* __restrict__ w3c, const float* __restrict__ w3d,
                          const float* __restrict__ w4, float* __restrict__ ws)
{
  const int idx = blockIdx.x * blockDim.x + threadIdx.x;
  const int stride = gridDim.x * blockDim.x;
  for (int i = idx; i < 1280; i += stride) ws[i] = 0.f;
  uint4* qq = (uint4*)(ws + OFF_PVOLB);
  for (int i = idx; i < 941192; i += stride) {
    int x = i % 98, t = i / 98, y = t % 98, z = t / 98;
    uint4 f; f.x = 0u; f.y = 0u; f.z = 0u; f.w = 0u;
    if (x >= 32 && x <= 64 && y >= 32 && y <= 64 && z >= 32 && z <= 64) {
      float c000 = corner(images, x, y, z),     c100 = corner(images, x+1, y, z);
      float c010 = corner(images, x, y+1, z),   c110 = corner(images, x+1, y+1, z);
      float c001 = corner(images, x, y, z+1),   c101 = corner(images, x+1, y, z+1);
      float c011 = corner(images, x, y+1, z+1), c111 = corner(images, x+1, y+1, z+1);
      f.x = (unsigned int)f2bf(c000) | ((unsigned int)f2bf(c100) << 16);
      f.y = (unsigned int)f2bf(c010) | ((unsigned int)f2bf(c110) << 16);
      f.z = (unsigned int)f2bf(c001) | ((unsigned int)f2bf(c101) << 16);
      f.w = (unsigned int)f2bf(c011) | ((unsigned int)f2bf(c111) << 16);
    }
    qq[i] = f;
  }
  int* c0a = (int*)(ws + OFF_C0A);
  for (int k = idx; k < 1024; k += stride) c0a[k] = tap_c0(offset1, k, 0);
  for (int i = idx; i < 4096;  i += stride) { int o = i & 31,  c = i >> 5; ws[OFF_W3AT + i] = w3a[o * 128 + c]; }
  for (int i = idx; i < 5120;  i += stride) { int o = i & 31,  c = i >> 5; ws[OFF_W3BT + i] = w3b[o * 160 + c]; }
  for (int i = idx; i < 6144;  i += stride) { int o = i & 31,  c = i >> 5; ws[OFF_W3CT + i] = w3c[o * 192 + c]; }
  for (int i = idx; i < 7168;  i += stride) { int o = i & 31,  c = i >> 5; ws[OFF_W3DT + i] = w3d[o * 224 + c]; }
  for (int i = idx; i < 2048;  i += stride) { int l = i & 7,   c = i >> 3; ws[OFF_W4T + i] = w4[l * 256 + c]; }
}

// ---------------- S0b: rank-sort taps by c0 within each group ----------------
__global__ void s0b_rank(float* __restrict__ ws)
{
  const int idx = blockIdx.x * blockDim.x + threadIdx.x;
  if (idx >= 1024) return;
  const int g = idx >> 8, k = idx & 255;
  const int* c0a = (const int*)(ws + OFF_C0A);
  int* perm = (int*)(ws + OFF_PERM);
  const int my = c0a[g * 256 + k];
  int rank = 0;
  for (int j = 0; j < 256; ++j) {
    int cj = c0a[g * 256 + j];
    rank += (cj < my) || (cj == my && j < k);
  }
  perm[g * 256 + rank] = k;
}

// ---------------- S0c: permuted tap params + bf16 A-frag packs (w1, w2) ----------------
__global__ void s0c_build(const float* __restrict__ offset1, const float* __restrict__ w1,
                          const float* __restrict__ w2, float* __restrict__ ws)
{
  const int idx = blockIdx.x * blockDim.x + threadIdx.x;
  const int stride = gridDim.x * blockDim.x;
  const int* perm = (const int*)(ws + OFF_PERM);
  for (int p = idx; p < 1024; p += stride) {
    const int g = p >> 8;
    const int k = g * 256 + perm[p];
    float* tp = ws + OFF_TPAR + p * 16;
    for (int s = 0; s < 2; ++s) {
      float ox = fminf(fmaxf(offset1[k * 6 + s * 3 + 0] * 16.f, -1000.f), 1000.f);
      float oy = fminf(fmaxf(offset1[k * 6 + s * 3 + 1] * 16.f, -1000.f), 1000.f);
      float oz = fminf(fmaxf(offset1[k * 6 + s * 3 + 2] * 16.f, -1000.f), 1000.f);
      float fxf = floorf(ox), fyf = floorf(oy), fzf = floorf(oz);
      float fx = ox - fxf, fy = oy - fyf, fz = oz - fzf;
      int sx = (int)fxf, sy = (int)fyf, sz = (int)fzf;
      bool valid = (sx >= -33 && sx <= 32) && (sy >= -33 && sy <= 32) && (sz >= -33 && sz <= 32);
      if (!valid) { sx = sy = sz = 0; }
      float vm = valid ? 1.f : 0.f;
      int c0 = (sz + 33) * 9604 + (sy + 33) * 98 + (sx + 33);
      float sgn = s ? -1.f : 1.f;
      float wy0 = 1.f - fy, wy1 = fy, wz0 = 1.f - fz, wz1 = fz;
      tp[s * 8 + 0] = __int_as_float(c0);
      tp[s * 8 + 1] = vm * (1.f - fx);
      tp[s * 8 + 2] = vm * fx;
      tp[s * 8 + 3] = vm * sgn * wz0 * wy0;
      tp[s * 8 + 4] = vm * sgn * wz0 * wy1;
      tp[s * 8 + 5] = vm * sgn * wz1 * wy0;
      tp[s * 8 + 6] = vm * sgn * wz1 * wy1;
      tp[s * 8 + 7] = 0.f;
    }
  }
  for (int i = idx; i < 32768; i += stride) {
    int jp = i & 3;
    int l  = (i >> 2) & 63;
    int ks = (i >> 8) & 7;
    int mt = (i >> 11) & 3;
    int g  = i >> 13;
    int row = mt * 16 + (l & 15);
    int kbase = g * 256 + ks * 32 + (l >> 4) * 8 + jp * 2;
    int ka = perm[kbase], kb = perm[kbase + 1];
    unsigned short b0 = f2bf(w1[g * 16384 + row * 256 + ka]);
    unsigned short b1 = f2bf(w1[g * 16384 + row * 256 + kb]);
    ws[OFF_W1A + i] = __uint_as_float((unsigned int)b0 | ((unsigned int)b1 << 16));
  }
  for (int i = idx; i < 16384; i += stride) {
    int jp = i & 3;
    int l  = (i >> 2) & 63;
    int ks = (i >> 8) & 7;
    int mt = i >> 11;              // 0..7
    int row = mt * 16 + (l & 15);
    int k = ks * 32 + (l >> 4) * 8 + jp * 2;
    unsigned short b0 = f2bf(w2[row * 256 + k]);
    unsigned short b1 = f2bf(w2[row * 256 + k + 1]);
    ws[OFF_W2A + i] = __uint_as_float((unsigned int)b0 | ((unsigned int)b1 << 16));
  }
}

// one tap from the bf16-cube volume: ONE uint4 load
__device__ __forceinline__ float tapB(const uint4* __restrict__ Q, int vbase,
                                      const float4 t0, const float4 t1)
{
  uint4 c = Q[vbase + __float_as_int(t0.x)];
  float c0 = __uint_as_float(c.x << 16), c1 = __uint_as_float(c.x & 0xffff0000u);
  float c2 = __uint_as_float(c.y << 16), c3 = __uint_as_float(c.y & 0xffff0000u);
  float c4 = __uint_as_float(c.z << 16), c5 = __uint_as_float(c.z & 0xffff0000u);
  float c6 = __uint_as_float(c.w << 16), c7 = __uint_as_float(c.w & 0xffff0000u);
  float h0 = c0 * t0.y + c1 * t0.z;
  float h1 = c2 * t0.y + c3 * t0.z;
  float h2 = c4 * t0.y + c5 * t0.z;
  float h3 = c6 * t0.y + c7 * t0.z;
  return h0 * t0.w + h1 * t1.x + h2 * t1.y + h3 * t1.z;
}

// ---------------- S1: fused gather + MFMA (proven 128-voxel version) ----------------
__global__ __launch_bounds__(256, 4) void s1_gather_gemm(
    const uint4* __restrict__ pvolB, const float* __restrict__ tparP,
    const float4* __restrict__ apack, float* __restrict__ y, float* __restrict__ stats_y)
{
  __shared__ unsigned short xt[128 * 72];   // 18432 B
  const int tid = threadIdx.x;
  const int lane = tid & 63;
  const int wv = tid >> 6;          // m-tile 0..3
  const int g = blockIdx.y;
  const int v0 = blockIdx.x * 128;
  const int n = tid & 127;
  const int khalf = tid >> 7;       // 0/1: k-half of chunk
  const int v = v0 + n;
  const int vbase = (v >> 10) * 9604 + ((v >> 5) & 31) * 98 + (v & 31);
  const float4* tq_base = (const float4*)(tparP + g * 4096);

  f32x4 acc[8];
  #pragma unroll
  for (int i = 0; i < 8; ++i) acc[i] = (f32x4){0.f, 0.f, 0.f, 0.f};

  for (int ch = 0; ch < 4; ++ch) {
    const int kb = ch * 64 + khalf * 32;
    __syncthreads();
    #pragma unroll 2
    for (int i2 = 0; i2 < 32; i2 += 2) {
      const int kt = kb + i2;
      float4 t0 = tq_base[kt*4+0], t1 = tq_base[kt*4+1];
      float4 t2 = tq_base[kt*4+2], t3 = tq_base[kt*4+3];
      float xv0 = tapB(pvolB, vbase, t0, t1) + tapB(pvolB, vbase, t2, t3);
      float4 u0 = tq_base[kt*4+4], u1 = tq_base[kt*4+5];
      float4 u2 = tq_base[kt*4+6], u3 = tq_base[kt*4+7];
      float xv1 = tapB(pvolB, vbase, u0, u1) + tapB(pvolB, vbase, u2, u3);
      unsigned int pk = (unsigned int)f2bf(xv0) | ((unsigned int)f2bf(xv1) << 16);
      *(unsigned int*)&xt[n * 72 + khalf * 32 + i2] = pk;
    }
    __syncthreads();
    #pragma unroll
    for (int s = 0; s < 2; ++s) {
      float4 araw = apack[(((g * 4 + wv) * 8) + ch * 2 + s) * 64 + lane];
      bf16x8 a = *reinterpret_cast<bf16x8*>(&araw);
      #pragma unroll
      for (int nt = 0; nt < 8; ++nt) {
        const unsigned short* bp = &xt[(nt * 16 + (lane & 15)) * 72 + s * 32 + (lane >> 4) * 8];
        float4 braw = *(const float4*)bp;
        bf16x8 b = *reinterpret_cast<bf16x8*>(&braw);
        acc[nt] = __builtin_amdgcn_mfma_f32_16x16x32_bf16(a, b, acc[nt], 0, 0, 0);
      }
    }
  }
  const int obase = g << 6;
  float srow0 = 0.f, srow1 = 0.f, srow2 = 0.f, srow3 = 0.f;
  float qrow0 = 0.f, qrow1 = 0.f, qrow2 = 0.f, qrow3 = 0.f;
  #pragma unroll
  for (int nt = 0; nt < 8; ++nt) {
    const int col = v0 + nt * 16 + (lane & 15);
    const int rbase = obase + wv * 16 + (lane >> 4) * 4;
    float e0 = acc[nt][0], e1 = acc[nt][1], e2 = acc[nt][2], e3 = acc[nt][3];
    y[(size_t)(rbase + 0) * VOXN + col] = e0;
    y[(size_t)(rbase + 1) * VOXN + col] = e1;
    y[(size_t)(rbase + 2) * VOXN + col] = e2;
    y[(size_t)(rbase + 3) * VOXN + col] = e3;
    srow0 += e0; qrow0 += e0 * e0;
    srow1 += e1; qrow1 += e1 * e1;
    srow2 += e2; qrow2 += e2 * e2;
    srow3 += e3; qrow3 += e3 * e3;
  }
  #define ROWRED(S, Q, R) { \
    float s_ = S, q_ = Q; \
    s_ += __shfl_xor(s_, 1, 64); q_ += __shfl_xor(q_, 1, 64); \
    s_ += __shfl_xor(s_, 2, 64); q_ += __shfl_xor(q_, 2, 64); \
    s_ += __shfl_xor(s_, 4, 64); q_ += __shfl_xor(q_, 4, 64); \
    s_ += __shfl_xor(s_, 8, 64); q_ += __shfl_xor(q_, 8, 64); \
    if ((lane & 15) == 0) { \
      int row = obase + wv * 16 + (lane >> 4) * 4 + (R); \
      atomicAdd(&stats_y[row], s_); atomicAdd(&stats_y[256 + row], q_); } }
  ROWRED(srow0, qrow0, 0) ROWRED(srow1, qrow1, 1)
  ROWRED(srow2, qrow2, 2) ROWRED(srow3, qrow3, 3)
  #undef ROWRED
}

// ---------------- S2: x1 = relu(BN(y)) -> bf16 -> MFMA vs w2, 64-output halves ----------
__global__ __launch_bounds__(256) void s2_bn_gemm(
    const float* __restrict__ y, const float* __restrict__ stats_y,
    const float* __restrict__ g1, const float* __restrict__ b1,
    const float4* __restrict__ w2a, float* __restrict__ x2p, float* __restrict__ stats_x2p)
{
  __shared__ float As[256], Bs[256];
  __shared__ unsigned short xt[128 * 72];   // 18432 B
  const int tid = threadIdx.x;
  const int lane = tid & 63;
  const int wv = tid >> 6;          // m-tile within half (0..3)
  const int n = tid & 127;
  const int khalf = tid >> 7;       // k-half of chunk
  const int half = blockIdx.y;      // 0/1: output half
  const int v0 = blockIdx.x * 128;
  const int v = v0 + n;
  {
    float m = stats_y[tid] * (1.f / VOXN);
    float vv = stats_y[256 + tid] * (1.f / VOXN) - m * m;
    float a = g1[tid] * rsqrtf(vv + 1e-5f);
    As[tid] = a; Bs[tid] = b1[tid] - m * a;
  }
  f32x4 acc[8];
  #pragma unroll
  for (int i = 0; i < 8; ++i) acc[i] = (f32x4){0.f, 0.f, 0.f, 0.f};

  for (int ch = 0; ch < 4; ++ch) {
    const int kb = ch * 64 + khalf * 32;
    __syncthreads();
    #pragma unroll 2
    for (int i2 = 0; i2 < 32; i2 += 2) {
      const int c = kb + i2;
      float t0 = fmaxf(fmaf(y[(size_t)c * VOXN + v], As[c], Bs[c]), 0.f);
      float t1 = fmaxf(fmaf(y[(size_t)(c + 1) * VOXN + v], As[c + 1], Bs[c + 1]), 0.f);
      unsigned int pk = (unsigned int)f2bf(t0) | ((unsigned int)f2bf(t1) << 16);
      *(unsigned int*)&xt[n * 72 + khalf * 32 + i2] = pk;
    }
    __syncthreads();
    #pragma unroll
    for (int s = 0; s < 2; ++s) {
      float4 araw = w2a[(((half * 4 + wv) * 8) + ch * 2 + s) * 64 + lane];
      bf16x8 a = *reinterpret_cast<bf16x8*>(&araw);
      #pragma unroll
      for (int nt = 0; nt < 8; ++nt) {
        const unsigned short* bp = &xt[(nt * 16 + (lane & 15)) * 72 + s * 32 + (lane >> 4) * 8];
        float4 braw = *(const float4*)bp;
        bf16x8 b = *reinterpret_cast<bf16x8*>(&braw);
        acc[nt] = __builtin_amdgcn_mfma_f32_16x16x32_bf16(a, b, acc[nt], 0, 0, 0);
      }
    }
  }
  const int mbase = half * 64 + wv * 16;
  float srow0 = 0.f, srow1 = 0.f, srow2 = 0.f, srow3 = 0.f;
  float qrow0 = 0.f, qrow1 = 0.f, qrow2 = 0.f, qrow3 = 0.f;
  #pragma unroll
  for (int nt = 0; nt < 8; ++nt) {
    const int col = v0 + nt * 16 + (lane & 15);
    const int rbase = mbase + (lane >> 4) * 4;
    float e0 = acc[nt][0], e1 = acc[nt][1], e2 = acc[nt][2], e3 = acc[nt][3];
    x2p[(size_t)(rbase + 0) * VOXN + col] = e0;
    x2p[(size_t)(rbase + 1) * VOXN + col] = e1;
    x2p[(size_t)(rbase + 2) * VOXN + col] = e2;
    x2p[(size_t)(rbase + 3) * VOXN + col] = e3;
    srow0 += e0; qrow0 += e0 * e0;
    srow1 += e1; qrow1 += e1 * e1;
    srow2 += e2; qrow2 += e2 * e2;
    srow3 += e3; qrow3 += e3 * e3;
  }
  #define ROWRED2(S, Q, R) { \
    float s_ = S, q_ = Q; \
    s_ += __shfl_xor(s_, 1, 64); q_ += __shfl_xor(q_, 1, 64); \
    s_ += __shfl_xor(s_, 2, 64); q_ += __shfl_xor(q_, 2, 64); \
    s_ += __shfl_xor(s_, 4, 64); q_ += __shfl_xor(q_, 4, 64); \
    s_ += __shfl_xor(s_, 8, 64); q_ += __shfl_xor(q_, 8, 64); \
    if ((lane & 15) == 0) { \
      int row = mbase + (lane >> 4) * 4 + (R); \
      atomicAdd(&stats_x2p[row], s_); atomicAdd(&stats_x2p[128 + row], q_); } }
  ROWRED2(srow0, qrow0, 0) ROWRED2(srow1, qrow1, 1)
  ROWRED2(srow2, qrow2, 2) ROWRED2(srow3, qrow3, 3)
  #undef ROWRED2
}

// fused-coefficient preamble helpers (x2 = a2*x2p + b2c; stats of x2 analytic)
__device__ __forceinline__ void x2_coef(const float* __restrict__ stats_x2p,
                                        const float* __restrict__ g2, const float* __restrict__ b2,
                                        int c, float& a2, float& b2c, float& mx, float& vx)
{
  float m2 = stats_x2p[c] * (1.f / VOXN);
  float v2 = stats_x2p[128 + c] * (1.f / VOXN) - m2 * m2;
  a2 = g2[c] * rsqrtf(v2 + 1e-5f);
  b2c = b2[c] - m2 * a2;
  mx = b2[c];
  vx = a2 * a2 * v2;
}

// ---------------- S3: ha = relu(w3a @ x2), x2 read fused from x2p. 8-way split ----------
__global__ __launch_bounds__(256) void s3_ha(
    const float* __restrict__ x2p, const float* __restrict__ stats_x2p,
    const float* __restrict__ g2, const float* __restrict__ b2,
    const float* __restrict__ w3at, float* __restrict__ H, float* __restrict__ stats_H)
{
  __shared__ float As[128], Bs[128];
  __shared__ float redS[4][4], redQ[4][4];
  const int tid = threadIdx.x;
  const int lane = tid & 63;
  const int wv = tid >> 6;
  if (tid < 128) {
    float a2, b2c, mx, vx;
    x2_coef(stats_x2p, g2, b2, tid, a2, b2c, mx, vx);
    As[tid] = a2; Bs[tid] = b2c;
  }
  __syncthreads();
  const int qh = blockIdx.y;           // 0..7 -> 4 outputs
  const int n = blockIdx.x * 256 + tid;
  ZERO4(a0)
  #pragma unroll 8
  for (int c = 0; c < 128; ++c) {
    float x2v = fmaf(x2p[(size_t)c * VOXN + n], As[c], Bs[c]);
    const float4* wk = (const float4*)(w3at + c * 32 + qh * 4);
    float4 w = wk[0];
    FMA4(a0, w, x2v)
  }
  RELU4(a0)
  const int ob = 128 + qh * 4;
  H[((size_t)(ob + 0)) * VOXN + n] = a0.x;
  H[((size_t)(ob + 1)) * VOXN + n] = a0.y;
  H[((size_t)(ob + 2)) * VOXN + n] = a0.z;
  H[((size_t)(ob + 3)) * VOXN + n] = a0.w;
  float ms = 0.f, mq = 0.f;
  STASH4(a0, 0)
  if (lane < 4) { redS[wv][lane] = ms; redQ[wv][lane] = mq; }
  __syncthreads();
  if (tid < 4) {
    float s = redS[0][tid] + redS[1][tid] + redS[2][tid] + redS[3][tid];
    float qq = redQ[0][tid] + redQ[1][tid] + redQ[2][tid] + redQ[3][tid];
    atomicAdd(&stats_H[ob + tid], s);
    atomicAdd(&stats_H[256 + ob + tid], qq);
  }
}

// ------- S4/5/6: h = relu(w @ BN([x2|H])) -> H[och + qh*4 ..]; c<128 fused from x2p -----
template<int CIN>
__global__ __launch_bounds__(256) void s_dense(
    const float* __restrict__ x2p, const float* __restrict__ stats_x2p,
    const float* __restrict__ g2, const float* __restrict__ b2,
    const float* __restrict__ Hin, const float* __restrict__ stats_H,
    const float* __restrict__ g, const float* __restrict__ b,
    const float* __restrict__ wt, float* __restrict__ H, float* __restrict__ stats_out, int och)
{
  __shared__ float As[CIN], Bs[CIN];
  __shared__ float redS[4][4], redQ[4][4];
  const int tid = threadIdx.x;
  const int lane = tid & 63;
  const int wv = tid >> 6;
  if (tid < 128) {
    float a2, b2c, mx, vx;
    x2_coef(stats_x2p, g2, b2, tid, a2, b2c, mx, vx);
    float A = g[tid] * rsqrtf(vx + 1e-5f);
    float B = b[tid] - mx * A;
    As[tid] = A * a2; Bs[tid] = fmaf(A, b2c, B);
  } else if (tid < CIN) {
    float m = stats_H[tid] * (1.f / VOXN);
    float vv = stats_H[256 + tid] * (1.f / VOXN) - m * m;
    float A = g[tid] * rsqrtf(vv + 1e-5f);
    As[tid] = A; Bs[tid] = b[tid] - m * A;
  }
  __syncthreads();
  const int osub = blockIdx.y * 4;     // 0..7 -> 4 outputs
  const int n = blockIdx.x * 256 + tid;
  ZERO4(a0)
  #pragma unroll 8
  for (int c = 0; c < 128; ++c) {
    float t = fmaf(x2p[(size_t)c * VOXN + n], As[c], Bs[c]);
    const float4* wk = (const float4*)(wt + c * 32 + osub);
    float4 w = wk[0];
    FMA4(a0, w, t)
  }
  #pragma unroll 8
  for (int c = 128; c < CIN; ++c) {
    float t = fmaf(Hin[(size_t)c * VOXN + n], As[c], Bs[c]);
    const float4* wk = (const float4*)(wt + c * 32 + osub);
    float4 w = wk[0];
    FMA4(a0, w, t)
  }
  RELU4(a0)
  const int ob = och + osub;
  H[((size_t)(ob + 0)) * VOXN + n] = a0.x;
  H[((size_t)(ob + 1)) * VOXN + n] = a0.y;
  H[((size_t)(ob + 2)) * VOXN + n] = a0.z;
  H[((size_t)(ob + 3)) * VOXN + n] = a0.w;
  float ms = 0.f, mq = 0.f;
  STASH4(a0, 0)
  if (lane < 4) { redS[wv][lane] = ms; redQ[wv][lane] = mq; }
  __syncthreads();
  if (tid < 4) {
    float s = redS[0][tid] + redS[1][tid] + redS[2][tid] + redS[3][tid];
    float qq = redQ[0][tid] + redQ[1][tid] + redQ[2][tid] + redQ[3][tid];
    atomicAdd(&stats_out[ob + tid], s);
    atomicAdd(&stats_out[256 + ob + tid], qq);
  }
}

// ---------------- S7: out = sigmoid(w4 @ BN([x2|H]) + b4); c<128 fused ------------------
__global__ __launch_bounds__(256) void s7_final(
    const float* __restrict__ x2p, const float* __restrict__ stats_x2p,
    const float* __restrict__ g2, const float* __restrict__ b2,
    const float* __restrict__ H, const float* __restrict__ stats_H,
    const float* __restrict__ g3d, const float* __restrict__ b3d,
    const float* __restrict__ w4t, const float* __restrict__ b4, float* __restrict__ out)
{
  __shared__ float As[256], Bs[256];
  __shared__ float part[3][64][8];
  const int tid = threadIdx.x;
  const int vox = tid & 63;
  const int cq = tid >> 6;              // c-quarter 0..3
  const int n = blockIdx.x * 64 + vox;
  if (tid < 128) {
    float a2, b2c, mx, vx;
    x2_coef(stats_x2p, g2, b2, tid, a2, b2c, mx, vx);
    float A = g3d[tid] * rsqrtf(vx + 1e-5f);
    float B = b3d[tid] - mx * A;
    As[tid] = A * a2; Bs[tid] = fmaf(A, b2c, B);
  } else {
    float m = stats_H[tid] * (1.f / VOXN);
    float vv = stats_H[256 + tid] * (1.f / VOXN) - m * m;
    float A = g3d[tid] * rsqrtf(vv + 1e-5f);
    As[tid] = A; Bs[tid] = b3d[tid] - m * A;
  }
  __syncthreads();
  ZERO4(a0) ZERO4(a1)
  const int c0 = cq * 64;
  #pragma unroll 8
  for (int c = c0; c < c0 + 64; ++c) {
    const float* src = (c < 128) ? x2p : (H - (size_t)0);
    float t = fmaf(src[(size_t)c * VOXN + n], As[c], Bs[c]);
    const float4* wk = (const float4*)(w4t + c * 8);
    float4 w;
    w = wk[0]; FMA4(a0, w, t)
    w = wk[1]; FMA4(a1, w, t)
  }
  if (cq > 0) {
    part[cq - 1][vox][0] = a0.x; part[cq - 1][vox][1] = a0.y;
    part[cq - 1][vox][2] = a0.z; part[cq - 1][vox][3] = a0.w;
    part[cq - 1][vox][4] = a1.x; part[cq - 1][vox][5] = a1.y;
    part[cq - 1][vox][6] = a1.z; part[cq - 1][vox][7] = a1.w;
  }
  __syncthreads();
  if (cq == 0) {
    float r0 = a0.x + part[0][vox][0] + part[1][vox][0] + part[2][vox][0];
    float r1 = a0.y + part[0][vox][1] + part[1][vox][1] + part[2][vox][1];
    float r2 = a0.z + part[0][vox][2] + part[1][vox][2] + part[2][vox][2];
    float r3 = a0.w + part[0][vox][3] + part[1][vox][3] + part[2][vox][3];
    float r4 = a1.x + part[0][vox][4] + part[1][vox][4] + part[2][vox][4];
    float r5 = a1.y + part[0][vox][5] + part[1][vox][5] + part[2][vox][5];
    float r6 = a1.z + part[0][vox][6] + part[1][vox][6] + part[2][vox][6];
    float r7 = a1.w + part[0][vox][7] + part[1][vox][7] + part[2][vox][7];
    out[(size_t)0 * VOXN + n] = 1.f / (1.f + expf(-(r0 + b4[0])));
    out[(size_t)1 * VOXN + n] = 1.f / (1.f + expf(-(r1 + b4[1])));
    out[(size_t)2 * VOXN + n] = 1.f / (1.f + expf(-(r2 + b4[2])));
    out[(size_t)3 * VOXN + n] = 1.f / (1.f + expf(-(r3 + b4[3])));
    out[(size_t)4 * VOXN + n] = 1.f / (1.f + expf(-(r4 + b4[4])));
    out[(size_t)5 * VOXN + n] = 1.f / (1.f + expf(-(r5 + b4[5])));
    out[(size_t)6 * VOXN + n] = 1.f / (1.f + expf(-(r6 + b4[6])));
    out[(size_t)7 * VOXN + n] = 1.f / (1.f + expf(-(r7 + b4[7])));
  }
}

extern "C" void kernel_launch(void* const* d_in, const int* in_sizes, int n_in,
                              void* d_out, int out_size, void* d_ws, size_t ws_size,
                              hipStream_t stream)
{
  const float* images  = (const float*)d_in[0];
  const float* offset1 = (const float*)d_in[1];
  const float* w1  = (const float*)d_in[2];
  const float* g1  = (const float*)d_in[3];
  const float* b1  = (const float*)d_in[4];
  const float* w2  = (const float*)d_in[5];
  const float* g2  = (const float*)d_in[6];
  const float* b2  = (const float*)d_in[7];
  const float* w3a = (const float*)d_in[8];
  const float* w3b = (const float*)d_in[9];
  const float* w3c = (const float*)d_in[10];
  const float* w3d = (const float*)d_in[11];
  const float* g3a = (const float*)d_in[12];
  const float* b3a = (const float*)d_in[13];
  const float* g3b = (const float*)d_in[14];
  const float* b3b = (const float*)d_in[15];
  const float* g3c = (const float*)d_in[16];
  const float* b3c = (const float*)d_in[17];
  const float* g3d = (const float*)d_in[18];
  const float* b3d = (const float*)d_in[19];
  const float* w4  = (const float*)d_in[20];
  const float* b4  = (const float*)d_in[21];

  float* ws  = (float*)d_ws;
  float* out = (float*)d_out;

  float* statsY = ws + OFF_STATS_Y;
  float* statsX = ws + OFF_STATS_X2P;
  float* statsH = ws + OFF_STATS_H;
  float* YH     = ws + OFF_YH;   // y, later H (channels 128..255)
  float* x2p    = ws + OFF_X2P;

  s0a_setup<<<dim3(256), dim3(256), 0, stream>>>(images, offset1, w3a, w3b, w3c, w3d, w4, ws);
  s0b_rank<<<dim3(4), dim3(256), 0, stream>>>(ws);
  s0c_build<<<dim3(64), dim3(256), 0, stream>>>(offset1, w1, w2, ws);
  s1_gather_gemm<<<dim3(256, 4), dim3(256), 0, stream>>>(
      (const uint4*)(ws + OFF_PVOLB), ws + OFF_TPAR,
      (const float4*)(ws + OFF_W1A), YH, statsY);
  s2_bn_gemm<<<dim3(256, 2), dim3(256), 0, stream>>>(
      YH, statsY, g1, b1, (const float4*)(ws + OFF_W2A), x2p, statsX);
  s3_ha<<<dim3(128, 8), dim3(256), 0, stream>>>(x2p, statsX, g2, b2, ws + OFF_W3AT, YH, statsH);
  s_dense<160><<<dim3(128, 8), dim3(256), 0, stream>>>(
      x2p, statsX, g2, b2, YH, statsH, g3a, b3a, ws + OFF_W3BT, YH, statsH, 160);
  s_dense<192><<<dim3(128, 8), dim3(256), 0, stream>>>(
      x2p, statsX, g2, b2, YH, statsH, g3b, b3b, ws + OFF_W3CT, YH, statsH, 192);
  s_dense<224><<<dim3(128, 8), dim3(256), 0, stream>>>(
      x2p, statsX, g2, b2, YH, statsH, g3c, b3c, ws + OFF_W3DT, YH, statsH, 224);
  s7_final<<<dim3(512), dim3(256), 0, stream>>>(
      x2p, statsX, g2, b2, YH, statsH, g3d, b3d, ws + OFF_W4T, b4, out);
}